// Round 3
// baseline (371.504 us; speedup 1.0000x reference)
//
#include <hip/hip_runtime.h>
#include <hip/hip_bf16.h>
#include <math.h>

using bf16 = __hip_bfloat16;
typedef __bf16 bf16x8 __attribute__((ext_vector_type(8)));
typedef short  short4v __attribute__((ext_vector_type(4)));
typedef float  f32x4  __attribute__((ext_vector_type(4)));

static constexpr int Lq = 2048, Nb = 2, E = 1024, Hh = 16, Dd = 64, Ff = 4096;
static constexpr int MT = Lq * Nb;          // 4096 tokens

__device__ __forceinline__ void async_lds16(const void* g, void* l) {
  __builtin_amdgcn_global_load_lds(
      (const __attribute__((address_space(1))) void*)g,
      (__attribute__((address_space(3))) void*)l, 16, 0, 0);
}
__device__ __forceinline__ bf16x8 ld8(const bf16* p) { return *(const bf16x8*)p; }
__device__ __forceinline__ short bfbits(float x) {
  bf16 t = __float2bfloat16(x);
  return *(short*)&t;
}
// fast gelu (tanh form, reduced): gelu(v) = v * t/(t+1),
// t = exp2(2.302208*(v + 0.044715 v^3)); max abs err ~1e-3
__device__ __forceinline__ float gelu_fast(float v) {
  const float y = fminf(2.302208f * (v + 0.044715f * v * v * v), 80.f);
  const float t = exp2f(y);
  return v * t / (t + 1.0f);
}

// ---------------------------------------------------------------------------
// Fused f32 -> bf16 cast of all 6 weight matrices in ONE dispatch.
// ---------------------------------------------------------------------------
__global__ __launch_bounds__(256) void cvt_all_kernel(
    const float* __restrict__ wq, const float* __restrict__ wk,
    const float* __restrict__ wv, const float* __restrict__ wout,
    const float* __restrict__ fc1w, const float* __restrict__ fc2w,
    bf16* __restrict__ wqkvb, bf16* __restrict__ woutb,
    bf16* __restrict__ f1wb, bf16* __restrict__ f2wb) {
  const int i = blockIdx.x * 256 + threadIdx.x;
  const float* src;
  bf16* dst;
  size_t off;
  if (i < 786432) {            // qkv: three E*E blocks concat in wqkvb
    const int r = i >> 18;     // 0,1,2
    off = (size_t)(i & 262143);
    src = (r == 0) ? wq : (r == 1) ? wk : wv;
    dst = wqkvb + (size_t)r * (E * E);
  } else if (i < 1048576) {
    off = (size_t)(i - 786432); src = wout; dst = woutb;
  } else if (i < 2097152) {
    off = (size_t)(i - 1048576); src = fc1w; dst = f1wb;
  } else {
    off = (size_t)(i - 2097152); src = fc2w; dst = f2wb;
  }
  float4 v = ((const float4*)src)[off];
  bf16 o4[4] = {__float2bfloat16(v.x), __float2bfloat16(v.y),
                __float2bfloat16(v.z), __float2bfloat16(v.w)};
  *(uint2*)(dst + 4 * off) = *(uint2*)o4;
}

// ---------------------------------------------------------------------------
// GEMM, templated on BK (32 = R9 body; 64 = R10 XOR-swizzled body).
// EPI 2: gelu_fast(acc+bias) -> bf16
// EPI 3: acc -> bf16 partial at z*MT*E (split-K, no bias)
// EPI 4: QKV packed outputs:
//   ncol<1024        -> Q (scaled) to outb = qk1[token][1024]
//   1024<=ncol<2048  -> K packed:  outk[hh][l>>6][d>>3][l&63][d&7]
//   ncol>=2048       -> V packed:  outv[hh][l>>6][(l>>3)&7][d][l&7]
//   (These are byte-identical to the attn kernel's KB/VB LDS images, so
//    attn staging is 1KB-contiguous global_load_lds — coalesced.)
// ---------------------------------------------------------------------------
template <int EPI, int BK>
__global__ __launch_bounds__(256) void gemm_bt(
    const bf16* __restrict__ A, const bf16* __restrict__ W,
    const float* __restrict__ b1, const float* __restrict__ b2,
    const float* __restrict__ b3, int Klen, int Kstride, int Nld,
    float qscale, int scut, bf16* __restrict__ outb,
    bf16* __restrict__ outv, bf16* __restrict__ outk) {
  __shared__ __align__(16) bf16 As[128 * BK];
  __shared__ __align__(16) bf16 Bs[128 * BK];
  const int tid = threadIdx.x;
  const int w = tid >> 6, lane = tid & 63;
  const int quad = lane >> 4, l16 = lane & 15;
  const int wm = (w >> 1) * 64, wn = (w & 1) * 64;
  const int m0 = blockIdx.y * 128, n0 = blockIdx.x * 128;
  const int koff = blockIdx.z * Klen;

  f32x4 acc[4][4];
#pragma unroll
  for (int i = 0; i < 4; i++)
#pragma unroll
    for (int j = 0; j < 4; j++)
#pragma unroll
      for (int r = 0; r < 4; r++) acc[i][j][r] = 0.f;

  if constexpr (BK == 32) {
    const int c0 = w * 64 + lane;
    const int c1 = c0 + 256;
    const size_t arow0 = (size_t)(m0 + (c0 >> 2)), arow1 = (size_t)(m0 + (c1 >> 2));
    const size_t brow0 = (size_t)(n0 + (c0 >> 2)), brow1 = (size_t)(n0 + (c1 >> 2));
    const int col0 = (c0 & 3) * 8, col1 = (c1 & 3) * 8;
    bf16* ldsA0 = &As[(w * 64) * 8];
    bf16* ldsA1 = &As[(256 + w * 64) * 8];
    bf16* ldsB0 = &Bs[(w * 64) * 8];
    bf16* ldsB1 = &Bs[(256 + w * 64) * 8];

    const int nk = Klen >> 5;
    for (int kt = 0; kt < nk; ++kt) {
      const int k0 = koff + kt * 32;
      async_lds16(A + arow0 * Kstride + k0 + col0, ldsA0);
      async_lds16(A + arow1 * Kstride + k0 + col1, ldsA1);
      async_lds16(W + brow0 * Kstride + k0 + col0, ldsB0);
      async_lds16(W + brow1 * Kstride + k0 + col1, ldsB1);
      __syncthreads();
      bf16x8 a[4], b[4];
#pragma unroll
      for (int i = 0; i < 4; i++) {
        a[i] = ld8(&As[(wm + i * 16 + l16) * 32 + quad * 8]);
        b[i] = ld8(&Bs[(wn + i * 16 + l16) * 32 + quad * 8]);
      }
#pragma unroll
      for (int i = 0; i < 4; i++)
#pragma unroll
        for (int j = 0; j < 4; j++)
          acc[i][j] = __builtin_amdgcn_mfma_f32_16x16x32_bf16(a[i], b[j], acc[i][j], 0, 0, 0);
      __syncthreads();
    }
  } else {  // BK == 64, XOR-swizzled (0 bank conflicts, R10-measured)
    const int rowoff = w * 8 + (lane >> 3);
    const int colsw = (((lane & 7) ^ (lane >> 3)) << 3);

    const int nk = Klen >> 6;
    for (int kt = 0; kt < nk; ++kt) {
      const int k0 = koff + (kt << 6);
#pragma unroll
      for (int r = 0; r < 4; r++) {
        async_lds16(A + (size_t)(m0 + r * 32 + rowoff) * Kstride + k0 + colsw,
                    As + (size_t)(r * 256 + w * 64) * 8);
        async_lds16(W + (size_t)(n0 + r * 32 + rowoff) * Kstride + k0 + colsw,
                    Bs + (size_t)(r * 256 + w * 64) * 8);
      }
      __syncthreads();
#pragma unroll
      for (int ksub = 0; ksub < 2; ksub++) {
        const int gx = ksub * 4 + quad;
        bf16x8 a[4], b[4];
#pragma unroll
        for (int i = 0; i < 4; i++) {
          const int ra = wm + i * 16 + l16;
          const int rb = wn + i * 16 + l16;
          a[i] = ld8(&As[(size_t)(ra * 8 + (gx ^ (l16 & 7))) * 8]);
          b[i] = ld8(&Bs[(size_t)(rb * 8 + (gx ^ (l16 & 7))) * 8]);
        }
#pragma unroll
        for (int i = 0; i < 4; i++)
#pragma unroll
          for (int j = 0; j < 4; j++)
            acc[i][j] = __builtin_amdgcn_mfma_f32_16x16x32_bf16(a[i], b[j], acc[i][j], 0, 0, 0);
      }
      __syncthreads();
    }
  }

  const size_t zoff = (EPI == 3) ? (size_t)blockIdx.z * ((size_t)MT * E) : 0;
#pragma unroll
  for (int i = 0; i < 4; i++) {
    const int mrow = m0 + wm + i * 16 + quad * 4;
#pragma unroll
    for (int j = 0; j < 4; j++) {
      const int ncol = n0 + wn + j * 16 + l16;
      float bv = 0.f;
      if constexpr (EPI != 3) {
        if (b3 != nullptr) {
          bv = (ncol < 1024) ? b1[ncol]
               : (ncol < 2048) ? b2[ncol - 1024] : b3[ncol - 2048];
        } else {
          bv = b1[ncol];
        }
      }
      const float sc = (ncol < scut) ? qscale : 1.0f;
#pragma unroll
      for (int r = 0; r < 4; r++) {
        float v = (acc[i][j][r] + bv) * sc;
        if constexpr (EPI == 2) {
          outb[(size_t)(mrow + r) * Nld + ncol] = __float2bfloat16(gelu_fast(v));
        } else if constexpr (EPI == 3) {
          outb[zoff + (size_t)(mrow + r) * Nld + ncol] = __float2bfloat16(v);
        } else {  // EPI 4: QKV packed
          const int tok = mrow + r, n = tok & 1, l = tok >> 1;
          if (ncol < 1024) {
            outb[(size_t)tok * 1024 + ncol] = __float2bfloat16(v);
          } else if (ncol < 2048) {
            const int h = (ncol - 1024) >> 6, d = ncol & 63;
            const int hh = n * 16 + h;
            outk[((((size_t)hh * 32 + (l >> 6)) * 8 + (d >> 3)) * 64 + (l & 63)) * 8 +
                 (d & 7)] = __float2bfloat16(v);
          } else {
            const int h = (ncol - 2048) >> 6, d = ncol & 63;
            const int hh = n * 16 + h;
            outv[((((size_t)hh * 32 + (l >> 6)) * 8 + ((l >> 3) & 7)) * 64 + d) * 8 +
                 (l & 7)] = __float2bfloat16(v);
          }
        }
      }
    }
  }
}

// ---------------------------------------------------------------------------
// 256x256 8-wave phase-interleaved GEMM (T2+T3+T4+T5), BK=64.
// out = gelu(A @ W^T + bias), A:[M][K] bf16, W:[NOUT][K] bf16.
// (structure comments: see round-0 version; verified this session)
// ---------------------------------------------------------------------------
template <int S, int H>
__device__ __forceinline__ void load_frags256(const char* Ab, const char* Bb,
                                              const int (&aoff)[8], const int (&boff)[4],
                                              bf16x8 (&a)[4], bf16x8 (&b)[4]) {
#pragma unroll
  for (int i = 0; i < 4; i++) a[i] = ld8((const bf16*)(Ab + S * 16384 + aoff[H * 4 + i]));
#pragma unroll
  for (int j = 0; j < 4; j++) b[j] = ld8((const bf16*)(Bb + S * 16384 + boff[j]));
}

template <int H>
__device__ __forceinline__ void mfma256(const bf16x8 (&a)[4], const bf16x8 (&b)[4],
                                        f32x4 (&acc)[8][4]) {
#pragma unroll
  for (int i = 0; i < 4; i++)
#pragma unroll
    for (int j = 0; j < 4; j++)
      acc[H * 4 + i][j] =
          __builtin_amdgcn_mfma_f32_16x16x32_bf16(a[i], b[j], acc[H * 4 + i][j], 0, 0, 0);
}

template <int K, int NOUT>
__global__ __launch_bounds__(512, 2) void gemm256_gelu(
    const bf16* __restrict__ A, const bf16* __restrict__ W,
    const float* __restrict__ bias, bf16* __restrict__ out) {
  extern __shared__ char smem[];
  constexpr int NKT = K / 64;
  static_assert(NKT >= 2, "need >=2 K-tiles");
  const int tid = threadIdx.x;
  const int w = tid >> 6, lane = tid & 63;
  const int quad = lane >> 4, l16 = lane & 15;
  const int wr = w >> 2, wc = w & 3;  // wave 2x4 grid; per-wave C = 128x64
  const int m0 = blockIdx.y * 256, n0 = blockIdx.x * 256;

  // --- staging geometry (per-thread source, linear LDS dest) ---
  const int o0 = tid << 4;          // byte in 16 KiB block, load 0
  const int o1 = o0 + 8192;         // load 1
  const int r0 = o0 >> 6, r1 = o1 >> 6;                       // row 0..255
  const int c0 = ((((o0 >> 4) & 3) ^ ((o0 >> 7) & 3)) << 3);  // logical k-col (bf16)
  const int c1 = ((((o1 >> 4) & 3) ^ ((o1 >> 7) & 3)) << 3);
  const bf16* Ag0 = A + (size_t)(m0 + r0) * K + c0;
  const bf16* Ag1 = A + (size_t)(m0 + r1) * K + c1;
  const bf16* Wg0 = W + (size_t)(n0 + r0) * K + c0;
  const bf16* Wg1 = W + (size_t)(n0 + r1) * K + c1;
  const int ldsw = w << 10;  // wave-uniform LDS base offset within a half

  // --- fragment LDS byte offsets (within one ksub block) ---
  int aoff[8], boff[4];
#pragma unroll
  for (int h = 0; h < 2; h++)
#pragma unroll
    for (int i = 0; i < 4; i++) {
      const int ra = wr * 128 + h * 64 + i * 16 + l16;
      aoff[h * 4 + i] = ra * 64 + ((quad ^ ((ra >> 1) & 3)) << 4);
    }
#pragma unroll
  for (int j = 0; j < 4; j++) {
    const int rb = wc * 64 + j * 16 + l16;
    boff[j] = rb * 64 + ((quad ^ ((rb >> 1) & 3)) << 4);
  }

  f32x4 acc[8][4];
#pragma unroll
  for (int i = 0; i < 8; i++)
#pragma unroll
    for (int j = 0; j < 4; j++)
#pragma unroll
      for (int r = 0; r < 4; r++) acc[i][j][r] = 0.f;

  // --- prologue: stage tile 0 into buf0, order Aks0,Bks0,Aks1,Bks1 ---
  {
    char* d = smem;
    async_lds16(Ag0, d + ldsw);
    async_lds16(Ag1, d + 8192 + ldsw);
    async_lds16(Wg0, d + 32768 + ldsw);
    async_lds16(Wg1, d + 32768 + 8192 + ldsw);
    async_lds16(Ag0 + 32, d + 16384 + ldsw);
    async_lds16(Ag1 + 32, d + 16384 + 8192 + ldsw);
    async_lds16(Wg0 + 32, d + 49152 + ldsw);
    async_lds16(Wg1 + 32, d + 49152 + 8192 + ldsw);
  }
  asm volatile("s_waitcnt vmcnt(4)" ::: "memory");  // Aks0,Bks0 of tile0 landed
  __builtin_amdgcn_s_barrier();

  for (int kt = 0; kt < NKT; ++kt) {
    const char* Ab = smem + ((kt & 1) << 16);
    const char* Bb = Ab + 32768;
    char* Sd = smem + (((kt + 1) & 1) << 16);
    const int kn = (kt + 1) << 6;  // next tile k-offset (elements)
    if (kt + 1 < NKT) {
      {  // ph1: ks0, C-half0; stage A-ks0(t+1)
        bf16x8 a[4], b[4];
        load_frags256<0, 0>(Ab, Bb, aoff, boff, a, b);
        async_lds16(Ag0 + kn, Sd + ldsw);
        async_lds16(Ag1 + kn, Sd + 8192 + ldsw);
        __builtin_amdgcn_s_barrier();
        __builtin_amdgcn_s_setprio(1);
        mfma256<0>(a, b, acc);
        __builtin_amdgcn_s_setprio(0);
        __builtin_amdgcn_sched_barrier(0);
        __builtin_amdgcn_s_barrier();
      }
      {  // ph2: ks0, C-half1; stage B-ks0(t+1); vmcnt(4)
        bf16x8 a[4], b[4];
        load_frags256<0, 1>(Ab, Bb, aoff, boff, a, b);
        async_lds16(Wg0 + kn, Sd + 32768 + ldsw);
        async_lds16(Wg1 + kn, Sd + 32768 + 8192 + ldsw);
        __builtin_amdgcn_s_barrier();
        __builtin_amdgcn_s_setprio(1);
        mfma256<1>(a, b, acc);
        __builtin_amdgcn_s_setprio(0);
        asm volatile("s_waitcnt vmcnt(4)" ::: "memory");
        __builtin_amdgcn_sched_barrier(0);
        __builtin_amdgcn_s_barrier();
      }
      {  // ph3: ks1, C-half0; stage A-ks1(t+1)
        bf16x8 a[4], b[4];
        load_frags256<1, 0>(Ab, Bb, aoff, boff, a, b);
        async_lds16(Ag0 + kn + 32, Sd + 16384 + ldsw);
        async_lds16(Ag1 + kn + 32, Sd + 16384 + 8192 + ldsw);
        __builtin_amdgcn_s_barrier();
        __builtin_amdgcn_s_setprio(1);
        mfma256<0>(a, b, acc);
        __builtin_amdgcn_s_setprio(0);
        __builtin_amdgcn_sched_barrier(0);
        __builtin_amdgcn_s_barrier();
      }
      {  // ph4: ks1, C-half1; stage B-ks1(t+1); vmcnt(4)
        bf16x8 a[4], b[4];
        load_frags256<1, 1>(Ab, Bb, aoff, boff, a, b);
        async_lds16(Wg0 + kn + 32, Sd + 49152 + ldsw);
        async_lds16(Wg1 + kn + 32, Sd + 49152 + 8192 + ldsw);
        __builtin_amdgcn_s_barrier();
        __builtin_amdgcn_s_setprio(1);
        mfma256<1>(a, b, acc);
        __builtin_amdgcn_s_setprio(0);
        asm volatile("s_waitcnt vmcnt(4)" ::: "memory");
        __builtin_amdgcn_sched_barrier(0);
        __builtin_amdgcn_s_barrier();
      }
    } else {  // last tile: no staging; ph2 must fully drain for ks1 reads
      {
        bf16x8 a[4], b[4];
        load_frags256<0, 0>(Ab, Bb, aoff, boff, a, b);
        __builtin_amdgcn_s_barrier();
        __builtin_amdgcn_s_setprio(1);
        mfma256<0>(a, b, acc);
        __builtin_amdgcn_s_setprio(0);
        __builtin_amdgcn_sched_barrier(0);
        __builtin_amdgcn_s_barrier();
      }
      {
        bf16x8 a[4], b[4];
        load_frags256<0, 1>(Ab, Bb, aoff, boff, a, b);
        __builtin_amdgcn_s_barrier();
        __builtin_amdgcn_s_setprio(1);
        mfma256<1>(a, b, acc);
        __builtin_amdgcn_s_setprio(0);
        asm volatile("s_waitcnt vmcnt(0)" ::: "memory");
        __builtin_amdgcn_sched_barrier(0);
        __builtin_amdgcn_s_barrier();
      }
      {
        bf16x8 a[4], b[4];
        load_frags256<1, 0>(Ab, Bb, aoff, boff, a, b);
        __builtin_amdgcn_s_barrier();
        __builtin_amdgcn_s_setprio(1);
        mfma256<0>(a, b, acc);
        __builtin_amdgcn_s_setprio(0);
        __builtin_amdgcn_sched_barrier(0);
        __builtin_amdgcn_s_barrier();
      }
      {
        bf16x8 a[4], b[4];
        load_frags256<1, 1>(Ab, Bb, aoff, boff, a, b);
        __builtin_amdgcn_s_barrier();
        __builtin_amdgcn_s_setprio(1);
        mfma256<1>(a, b, acc);
        __builtin_amdgcn_s_setprio(0);
      }
    }
  }

  // epilogue: gelu(acc + bias) -> bf16  (same mapping as verified gemm_bt)
#pragma unroll
  for (int j = 0; j < 4; j++) {
    const int col = n0 + wc * 64 + j * 16 + l16;
    const float bv = bias[col];
#pragma unroll
    for (int mI = 0; mI < 8; mI++) {
      const int row = m0 + wr * 128 + mI * 16 + quad * 4;
#pragma unroll
      for (int r = 0; r < 4; r++) {
        out[(size_t)(row + r) * NOUT + col] =
            __float2bfloat16(gelu_fast(acc[mI][j][r] + bv));
      }
    }
  }
}

// ---------------------------------------------------------------------------
// Split-K reduce: out[i] = P0[i] + P1[i] + bias[col] + res[i]   (f32 out)
// ---------------------------------------------------------------------------
__global__ __launch_bounds__(256) void reduce2_kernel(
    const bf16* __restrict__ P, const float* __restrict__ bias,
    const float* __restrict__ res, float* __restrict__ out) {
  const int i = blockIdx.x * 256 + threadIdx.x;  // float4 index
  const size_t e0 = (size_t)i * 4;
  const int col = (int)(e0 & (E - 1));
  uint2 u0 = *(const uint2*)(P + e0);
  uint2 u1 = *(const uint2*)(P + (size_t)MT * E + e0);
  const bf16* p0 = (const bf16*)&u0;
  const bf16* p1 = (const bf16*)&u1;
  float4 b = *(const float4*)(bias + col);
  float4 r = *(const float4*)(res + e0);
  float4 o;
  o.x = (float)p0[0] + (float)p1[0] + b.x + r.x;
  o.y = (float)p0[1] + (float)p1[1] + b.y + r.y;
  o.z = (float)p0[2] + (float)p1[2] + b.z + r.z;
  o.w = (float)p0[3] + (float)p1[3] + b.w + r.w;
  *(float4*)(out + e0) = o;
}

// ---------------------------------------------------------------------------
// Fused out-proj reduce + LayerNorm2. One block per token.
// ---------------------------------------------------------------------------
__global__ __launch_bounds__(256) void redln_kernel(
    const bf16* __restrict__ P, const float* __restrict__ bias,
    const float* __restrict__ res, const float* __restrict__ wgt,
    const float* __restrict__ bia, float* __restrict__ x1,
    bf16* __restrict__ h2) {
  const int t = blockIdx.x, tid = threadIdx.x;
  const size_t base = (size_t)t * E;
  const int e0 = tid * 4;
  uint2 u0 = *(const uint2*)(P + base + e0);
  uint2 u1 = *(const uint2*)(P + (size_t)MT * E + base + e0);
  const bf16* p0 = (const bf16*)&u0;
  const bf16* p1 = (const bf16*)&u1;
  float4 b = *(const float4*)(bias + e0);
  float4 r = *(const float4*)(res + base + e0);
  float v4[4];
  v4[0] = (float)p0[0] + (float)p1[0] + b.x + r.x;
  v4[1] = (float)p0[1] + (float)p1[1] + b.y + r.y;
  v4[2] = (float)p0[2] + (float)p1[2] + b.z + r.z;
  v4[3] = (float)p0[3] + (float)p1[3] + b.w + r.w;
  *(float4*)(x1 + base + e0) = *(float4*)v4;

  float s = 0.f, ss = 0.f;
#pragma unroll
  for (int i = 0; i < 4; i++) { s += v4[i]; ss += v4[i] * v4[i]; }
  for (int off = 32; off > 0; off >>= 1) {
    s += __shfl_down(s, off, 64);
    ss += __shfl_down(ss, off, 64);
  }
  __shared__ float rs[4], rss[4], mv[2];
  const int w = tid >> 6;
  if ((tid & 63) == 0) { rs[w] = s; rss[w] = ss; }
  __syncthreads();
  if (tid == 0) {
    float S = rs[0] + rs[1] + rs[2] + rs[3];
    float SS = rss[0] + rss[1] + rss[2] + rss[3];
    float mean = S * (1.f / E);
    float var = SS * (1.f / E) - mean * mean;
    mv[0] = mean; mv[1] = rsqrtf(var + 1e-5f);
  }
  __syncthreads();
  const float mean = mv[0], rstd = mv[1];
  float4 wg = *(const float4*)(wgt + e0);
  float4 bb = *(const float4*)(bia + e0);
  bf16 o4[4];
  o4[0] = __float2bfloat16((v4[0] - mean) * rstd * wg.x + bb.x);
  o4[1] = __float2bfloat16((v4[1] - mean) * rstd * wg.y + bb.y);
  o4[2] = __float2bfloat16((v4[2] - mean) * rstd * wg.z + bb.z);
  o4[3] = __float2bfloat16((v4[3] - mean) * rstd * wg.w + bb.w);
  *(uint2*)(h2 + base + e0) = *(uint2*)o4;
}

// ---------------------------------------------------------------------------
// LayerNorm over E=1024 per token (f32 in, bf16 out). One block per token.
// ---------------------------------------------------------------------------
__global__ __launch_bounds__(256) void ln_kernel(
    const float* __restrict__ x, const float* __restrict__ wgt,
    const float* __restrict__ bia, bf16* __restrict__ out) {
  const int t = blockIdx.x, tid = threadIdx.x;
  const size_t base = (size_t)t * E;
  float v4[4], s = 0.f, ss = 0.f;
#pragma unroll
  for (int i = 0; i < 4; i++) {
    float v = x[base + i * 256 + tid];
    v4[i] = v; s += v; ss += v * v;
  }
  for (int off = 32; off > 0; off >>= 1) {
    s += __shfl_down(s, off, 64);
    ss += __shfl_down(ss, off, 64);
  }
  __shared__ float rs[4], rss[4], mv[2];
  const int w = tid >> 6;
  if ((tid & 63) == 0) { rs[w] = s; rss[w] = ss; }
  __syncthreads();
  if (tid == 0) {
    float S = rs[0] + rs[1] + rs[2] + rs[3];
    float SS = rss[0] + rss[1] + rss[2] + rss[3];
    float mean = S * (1.f / E);
    float var = SS * (1.f / E) - mean * mean;
    mv[0] = mean; mv[1] = rsqrtf(var + 1e-5f);
  }
  __syncthreads();
  const float mean = mv[0], rstd = mv[1];
#pragma unroll
  for (int i = 0; i < 4; i++) {
    const int e = i * 256 + tid;
    float r = (v4[i] - mean) * rstd * wgt[e] + bia[e];
    out[base + e] = __float2bfloat16(r);
  }
}

// ---------------------------------------------------------------------------
// Flash attention v11: v10 schedule + COALESCED staging from packed K/V.
// KT[hh][kblk][dchunk:8][tok:64][8] and VT[hh][kblk][kchunk:8][d:64][8] are
// byte-identical to the KB/VB LDS images, so each wave stages 2x 1KB
// contiguous chunks per buffer (16 cache lines per load instr, not 64).
// ---------------------------------------------------------------------------
__global__ __launch_bounds__(256) void attn_kernel(
    const bf16* __restrict__ Q1, const bf16* __restrict__ KT,
    const bf16* __restrict__ VT, bf16* __restrict__ O) {
  __shared__ __align__(16) bf16 KB[2][512 * 8];  // 2 x 8 KB
  __shared__ __align__(16) bf16 VB[2][512 * 8];  // 2 x 8 KB
  const int tid = threadIdx.x;
  const int w = tid >> 6, lane = tid & 63, quad = lane >> 4, l16 = lane & 15;
  const int bid = blockIdx.x;          // 0..1023
  const int x = bid & 7;
  const int m = (bid >> 3) & 31;
  const int g = bid >> 8;              // 0..3
  const int j = m >> 2;                // 0..7
  const int hh = (m & 3) * 8 + x;      // 0..31
  const int qt = (g == 0) ? j : (g == 1) ? (31 - j) : (g == 2) ? (j + 8) : (23 - j);
  const int n = hh >> 4, h = hh & 15;

  const bf16* Qp = Q1 + n * E + h * Dd;                    // row stride 2048
  const bf16* Kb = KT + (size_t)hh * 32 * 4096;            // 8KB per k-tile
  const bf16* Vb = VT + (size_t)hh * 32 * 4096;
  const int so = w * 512 + lane * 8;  // per-lane staging src offset (elems)

  const int ql = qt * 64 + w * 16 + l16;
  const bf16x8 aq0 = ld8(Qp + (size_t)ql * 2048 + quad * 8);
  const bf16x8 aq1 = ld8(Qp + (size_t)ql * 2048 + 32 + quad * 8);
  // Drain Q loads once so the loop's vmcnt ledger counts staging loads only.
  asm volatile("s_waitcnt vmcnt(0)" ::: "memory");

  // prologue: stage tile 0 -> buf 0 (coalesced 1KB chunks)
  async_lds16(Kb + so, &KB[0][w * 512]);
  async_lds16(Kb + 2048 + so, &KB[0][2048 + w * 512]);
  async_lds16(Vb + so, &VB[0][w * 512]);
  async_lds16(Vb + 2048 + so, &VB[0][2048 + w * 512]);

  f32x4 o_acc[4];
#pragma unroll
  for (int d = 0; d < 4; d++)
#pragma unroll
    for (int r = 0; r < 4; r++) o_acc[d][r] = 0.f;
  float m_run = -3e30f, l_run = 0.f;

  for (int kt = 0; kt <= qt; ++kt) {
    const bf16* KBb = KB[kt & 1];
    const bf16* VBb = VB[kt & 1];
    if (kt < qt) {
      const size_t tb = (size_t)(kt + 1) * 4096;
      bf16* Kd = &KB[(kt & 1) ^ 1][0];
      bf16* Vd = &VB[(kt & 1) ^ 1][0];
      async_lds16(Kb + tb + so, Kd + w * 512);
      async_lds16(Kb + tb + 2048 + so, Kd + 2048 + w * 512);
      async_lds16(Vb + tb + so, Vd + w * 512);
      async_lds16(Vb + tb + 2048 + so, Vd + 2048 + w * 512);
      asm volatile("s_waitcnt vmcnt(4)" ::: "memory");
    } else {
      asm volatile("s_waitcnt vmcnt(0)" ::: "memory");
    }
    __builtin_amdgcn_s_barrier();

    // ---- QK^T ----
    f32x4 s[4];
    __builtin_amdgcn_s_setprio(1);
#pragma unroll
    for (int ks = 0; ks < 4; ks++) {
      const bf16x8 kc0 = ld8(&KBb[(size_t)((quad)*64 + ks * 16 + l16) * 8]);
      const bf16x8 kc1 = ld8(&KBb[(size_t)((4 + quad) * 64 + ks * 16 + l16) * 8]);
#pragma unroll
      for (int r = 0; r < 4; r++) s[ks][r] = 0.f;
      s[ks] = __builtin_amdgcn_mfma_f32_16x16x32_bf16(kc0, aq0, s[ks], 0, 0, 0);
      s[ks] = __builtin_amdgcn_mfma_f32_16x16x32_bf16(kc1, aq1, s[ks], 0, 0, 0);
    }
    __builtin_amdgcn_s_setprio(0);

    if (kt == qt) {
#pragma unroll
      for (int ks = 0; ks < 4; ks++) {
#pragma unroll
        for (int r = 0; r < 4; r++) {
          const int kg = kt * 64 + ks * 16 + quad * 4 + r;
          if (kg > ql) s[ks][r] = -14427.0f;
        }
      }
    }

    // ---- online softmax (defer-max, THR=8 in exp2 domain) ----
    float tmax = s[0][0];
#pragma unroll
    for (int ks = 0; ks < 4; ks++)
#pragma unroll
      for (int r = 0; r < 4; r++) tmax = fmaxf(tmax, s[ks][r]);
    tmax = fmaxf(tmax, __shfl_xor(tmax, 16, 64));
    tmax = fmaxf(tmax, __shfl_xor(tmax, 32, 64));
    float mbase = m_run;
    if (__any(tmax - m_run > 8.0f)) {  // wave-uniform branch
      const float mnew = fmaxf(m_run, tmax);
      const float alpha = exp2f(m_run - mnew);
      m_run = mnew;
      mbase = mnew;
      l_run *= alpha;
#pragma unroll
      for (int d = 0; d < 4; d++)
#pragma unroll
        for (int r = 0; r < 4; r++) o_acc[d][r] *= alpha;
    }
    float rsum = 0.f;
    short4v pf[4];
#pragma unroll
    for (int ks = 0; ks < 4; ks++) {
#pragma unroll
      for (int r = 0; r < 4; r++) {
        const float pv = exp2f(s[ks][r] - mbase);
        rsum += pv;
        pf[ks][r] = bfbits(pv);
      }
    }
    rsum += __shfl_xor(rsum, 16, 64);
    rsum += __shfl_xor(rsum, 32, 64);
    l_run += rsum;

    // ---- PV ----
    __builtin_amdgcn_s_setprio(1);
#pragma unroll
    for (int d = 0; d < 4; d++) {
#pragma unroll
      for (int ks = 0; ks < 4; ks++) {
        const int gg = ks * 2 + (quad >> 1);
        const short4v av =
            *(const short4v*)&VBb[(size_t)(gg * 64 + d * 16 + l16) * 8 + (quad & 1) * 4];
        o_acc[d] = __builtin_amdgcn_mfma_f32_16x16x16bf16_1k(av, pf[ks], o_acc[d], 0, 0, 0);
      }
    }
    __builtin_amdgcn_s_setprio(0);

    __builtin_amdgcn_sched_barrier(0);
    __builtin_amdgcn_s_barrier();
  }

  const float inv_l = 1.f / fmaxf(l_run, 1e-30f);
  const size_t obase = (size_t)ql * (Nb * E) + (size_t)n * E + h * Dd;
#pragma unroll
  for (int d = 0; d < 4; d++)
#pragma unroll
    for (int r = 0; r < 4; r++)
      O[obase + d * 16 + quad * 4 + r] = __float2bfloat16(o_acc[d][r] * inv_l);
}

// ---------------------------------------------------------------------------
extern "C" void kernel_launch(void* const* d_in, const int* in_sizes, int n_in,
                              void* d_out, int out_size, void* d_ws, size_t ws_size,
                              hipStream_t stream) {
  const float* x    = (const float*)d_in[0];
  const float* ln1w = (const float*)d_in[1];
  const float* ln1b = (const float*)d_in[2];
  const float* wq   = (const float*)d_in[3];
  const float* bq   = (const float*)d_in[4];
  const float* wk   = (const float*)d_in[5];
  const float* bk   = (const float*)d_in[6];
  const float* wv   = (const float*)d_in[7];
  const float* bv   = (const float*)d_in[8];
  const float* wout = (const float*)d_in[9];
  const float* bout = (const float*)d_in[10];
  const float* ln2w = (const float*)d_in[11];
  const float* ln2b = (const float*)d_in[12];
  const float* fc1w = (const float*)d_in[13];
  const float* fc1b = (const float*)d_in[14];
  const float* fc2w = (const float*)d_in[15];
  const float* fc2b = (const float*)d_in[16];

  char* ws = (char*)d_ws;
  bf16* wqkvb = (bf16*)(ws);                        // 0-6 MB  [wq;wk;wv]
  bf16* woutb = (bf16*)(ws + ((size_t)6 << 20));    // 6-8 MB
  bf16* f1wb  = (bf16*)(ws + ((size_t)8 << 20));    // 8-16 MB
  bf16* f2wb  = (bf16*)(ws + ((size_t)16 << 20));   // 16-24 MB
  bf16* h1    = (bf16*)(ws + ((size_t)24 << 20));   // 24-32 MB (h2 reuses)
  bf16* qk1   = (bf16*)(ws + ((size_t)32 << 20));   // 32-40 MB Q [4096][1024]
  bf16* ktg   = (bf16*)(ws + ((size_t)40 << 20));   // 40-48 MB K packed
  bf16* vtg   = (bf16*)(ws + ((size_t)48 << 20));   // 48-56 MB V packed
  bf16* o     = (bf16*)(ws + ((size_t)56 << 20));   // 56-64 MB
  float* x1   = (float*)(ws + ((size_t)64 << 20));  // 64-80 MB f32
  bf16* Pout  = (bf16*)(ws + ((size_t)32 << 20));   // 32-48: out-proj splitK
  bf16* P01   = (bf16*)(ws);                        // 0-16: FC2 splitK partials
  bf16* f1    = (bf16*)(ws + ((size_t)32 << 20));   // 32-64 (qk1,ktg,vtg,o dead)
  bf16* h2    = h1;
  float* outp = (float*)d_out;

  static bool g_shmem_attr = false;
  if (!g_shmem_attr) {
    hipFuncSetAttribute(reinterpret_cast<const void*>(gemm256_gelu<1024, 4096>),
                        hipFuncAttributeMaxDynamicSharedMemorySize, 131072);
    g_shmem_attr = true;
  }

  cvt_all_kernel<<<12288, 256, 0, stream>>>(wq, wk, wv, wout, fc1w, fc2w,
                                            wqkvb, woutb, f1wb, f2wb);

  ln_kernel<<<MT, 256, 0, stream>>>(x, ln1w, ln1b, h1);

  dim3 gQKV(3 * E / 128, MT / 128);   // (24,32)
  dim3 gE2(E / 128, MT / 128, 2);     // (8,32,2) split-K

  // q pre-scale folded with log2(e) for exp2-domain softmax
  gemm_bt<4, 64><<<gQKV, 256, 0, stream>>>(h1, wqkvb, bq, bk, bv, E, E, 2048,
                                           0.125f * 1.44269504f, 1024, qk1, vtg, ktg);

  attn_kernel<<<1024, 256, 0, stream>>>(qk1, ktg, vtg, o);

  gemm_bt<3, 64><<<gE2, 256, 0, stream>>>(o, woutb, nullptr, nullptr, nullptr,
                                          E / 2, E, E, 1.f, 0, Pout, nullptr, nullptr);
  redln_kernel<<<MT, 256, 0, stream>>>(Pout, bout, x, ln2w, ln2b, x1, h2);

  // FC1: 256x256 8-wave phase-interleaved kernel
  gemm256_gelu<1024, 4096><<<dim3(Ff / 256, MT / 256), 512, 131072, stream>>>(
      h2, f1wb, fc1b, f1);

  gemm_bt<3, 64><<<gE2, 256, 0, stream>>>(f1, f2wb, nullptr, nullptr, nullptr,
                                          Ff / 2, Ff, E, 1.f, 0, P01, nullptr, nullptr);
  reduce2_kernel<<<MT * E / 1024, 256, 0, stream>>>(P01, fc2b, x1, outp);
}

// Round 4
// 367.397 us; speedup vs baseline: 1.0112x; 1.0112x over previous
//
#include <hip/hip_runtime.h>
#include <hip/hip_bf16.h>
#include <math.h>

using bf16 = __hip_bfloat16;
typedef __bf16 bf16x8 __attribute__((ext_vector_type(8)));
typedef short  short4v __attribute__((ext_vector_type(4)));
typedef float  f32x4  __attribute__((ext_vector_type(4)));

static constexpr int Lq = 2048, Nb = 2, E = 1024, Hh = 16, Dd = 64, Ff = 4096;
static constexpr int MT = Lq * Nb;          // 4096 tokens

__device__ __forceinline__ void async_lds16(const void* g, void* l) {
  __builtin_amdgcn_global_load_lds(
      (const __attribute__((address_space(1))) void*)g,
      (__attribute__((address_space(3))) void*)l, 16, 0, 0);
}
__device__ __forceinline__ bf16x8 ld8(const bf16* p) { return *(const bf16x8*)p; }
__device__ __forceinline__ short bfbits(float x) {
  bf16 t = __float2bfloat16(x);
  return *(short*)&t;
}
// fast gelu (tanh form, reduced): gelu(v) = v * t/(t+1),
// t = exp2(2.302208*(v + 0.044715 v^3)); max abs err ~1e-3
__device__ __forceinline__ float gelu_fast(float v) {
  const float y = fminf(2.302208f * (v + 0.044715f * v * v * v), 80.f);
  const float t = exp2f(y);
  return v * t / (t + 1.0f);
}

// ---------------------------------------------------------------------------
// Fused f32 -> bf16 cast of all 6 weight matrices in ONE dispatch.
// ---------------------------------------------------------------------------
__global__ __launch_bounds__(256) void cvt_all_kernel(
    const float* __restrict__ wq, const float* __restrict__ wk,
    const float* __restrict__ wv, const float* __restrict__ wout,
    const float* __restrict__ fc1w, const float* __restrict__ fc2w,
    bf16* __restrict__ wqkvb, bf16* __restrict__ woutb,
    bf16* __restrict__ f1wb, bf16* __restrict__ f2wb) {
  const int i = blockIdx.x * 256 + threadIdx.x;
  const float* src;
  bf16* dst;
  size_t off;
  if (i < 786432) {            // qkv: three E*E blocks concat in wqkvb
    const int r = i >> 18;     // 0,1,2
    off = (size_t)(i & 262143);
    src = (r == 0) ? wq : (r == 1) ? wk : wv;
    dst = wqkvb + (size_t)r * (E * E);
  } else if (i < 1048576) {
    off = (size_t)(i - 786432); src = wout; dst = woutb;
  } else if (i < 2097152) {
    off = (size_t)(i - 1048576); src = fc1w; dst = f1wb;
  } else {
    off = (size_t)(i - 2097152); src = fc2w; dst = f2wb;
  }
  float4 v = ((const float4*)src)[off];
  bf16 o4[4] = {__float2bfloat16(v.x), __float2bfloat16(v.y),
                __float2bfloat16(v.z), __float2bfloat16(v.w)};
  *(uint2*)(dst + 4 * off) = *(uint2*)o4;
}

// ---------------------------------------------------------------------------
// 256x256 8-wave phase-interleaved GEMM (T2+T3+T4+T5), BK=64. Generalized:
//   gemm256<K, KSTR, NOUT, EPI>: per-block K-extent, row stride of A/W,
//   output column count, epilogue. koff = blockIdx.z * K (split-K).
// EPI 2: gelu(acc + b1[col]) -> bf16 o0[row][NOUT]
// EPI 3: bf16 partial -> {o0,o1,o2,o3}[blockIdx.z][row][NOUT]  (no bias)
// EPI 4: QKV: 256-col tile lies in one segment (n0>>10): Q->(acc+b)*qs to
//        o0[tok][1024]; K packed -> o2[hh][l>>6][d>>3][l&63][d&7];
//        V packed -> o1[hh][l>>6][(l>>3)&7][d][l&7]  (attn LDS images)
// Schedule/LDS/swizzle identical to the round-1-verified kernel.
// ---------------------------------------------------------------------------
template <int S, int H>
__device__ __forceinline__ void load_frags256(const char* Ab, const char* Bb,
                                              const int (&aoff)[8], const int (&boff)[4],
                                              bf16x8 (&a)[4], bf16x8 (&b)[4]) {
#pragma unroll
  for (int i = 0; i < 4; i++) a[i] = ld8((const bf16*)(Ab + S * 16384 + aoff[H * 4 + i]));
#pragma unroll
  for (int j = 0; j < 4; j++) b[j] = ld8((const bf16*)(Bb + S * 16384 + boff[j]));
}

template <int H>
__device__ __forceinline__ void mfma256(const bf16x8 (&a)[4], const bf16x8 (&b)[4],
                                        f32x4 (&acc)[8][4]) {
#pragma unroll
  for (int i = 0; i < 4; i++)
#pragma unroll
    for (int j = 0; j < 4; j++)
      acc[H * 4 + i][j] =
          __builtin_amdgcn_mfma_f32_16x16x32_bf16(a[i], b[j], acc[H * 4 + i][j], 0, 0, 0);
}

template <int K, int KSTR, int NOUT, int EPI>
__global__ __launch_bounds__(512, 2) void gemm256(
    const bf16* __restrict__ A, const bf16* __restrict__ W,
    const float* __restrict__ b1, const float* __restrict__ b2,
    const float* __restrict__ b3, float qscale,
    bf16* __restrict__ o0, bf16* __restrict__ o1,
    bf16* __restrict__ o2, bf16* __restrict__ o3) {
  extern __shared__ char smem[];
  constexpr int NKT = K / 64;
  static_assert(NKT >= 2, "need >=2 K-tiles");
  const int tid = threadIdx.x;
  const int w = tid >> 6, lane = tid & 63;
  const int quad = lane >> 4, l16 = lane & 15;
  const int wr = w >> 2, wc = w & 3;  // wave 2x4 grid; per-wave C = 128x64
  const int m0 = blockIdx.y * 256, n0 = blockIdx.x * 256;
  const int koff = blockIdx.z * K;

  // --- staging geometry (per-thread source, linear LDS dest) ---
  const int o0b = tid << 4;         // byte in 16 KiB block, load 0
  const int o1b = o0b + 8192;       // load 1
  const int r0 = o0b >> 6, r1 = o1b >> 6;                       // row 0..255
  const int c0 = ((((o0b >> 4) & 3) ^ ((o0b >> 7) & 3)) << 3);  // k-col (bf16)
  const int c1 = ((((o1b >> 4) & 3) ^ ((o1b >> 7) & 3)) << 3);
  const bf16* Ag0 = A + (size_t)(m0 + r0) * KSTR + koff + c0;
  const bf16* Ag1 = A + (size_t)(m0 + r1) * KSTR + koff + c1;
  const bf16* Wg0 = W + (size_t)(n0 + r0) * KSTR + koff + c0;
  const bf16* Wg1 = W + (size_t)(n0 + r1) * KSTR + koff + c1;
  const int ldsw = w << 10;  // wave-uniform LDS base offset within a half

  // --- fragment LDS byte offsets (within one ksub block) ---
  int aoff[8], boff[4];
#pragma unroll
  for (int h = 0; h < 2; h++)
#pragma unroll
    for (int i = 0; i < 4; i++) {
      const int ra = wr * 128 + h * 64 + i * 16 + l16;
      aoff[h * 4 + i] = ra * 64 + ((quad ^ ((ra >> 1) & 3)) << 4);
    }
#pragma unroll
  for (int j = 0; j < 4; j++) {
    const int rb = wc * 64 + j * 16 + l16;
    boff[j] = rb * 64 + ((quad ^ ((rb >> 1) & 3)) << 4);
  }

  f32x4 acc[8][4];
#pragma unroll
  for (int i = 0; i < 8; i++)
#pragma unroll
    for (int j = 0; j < 4; j++)
#pragma unroll
      for (int r = 0; r < 4; r++) acc[i][j][r] = 0.f;

  // --- prologue: stage tile 0 into buf0, order Aks0,Bks0,Aks1,Bks1 ---
  {
    char* d = smem;
    async_lds16(Ag0, d + ldsw);
    async_lds16(Ag1, d + 8192 + ldsw);
    async_lds16(Wg0, d + 32768 + ldsw);
    async_lds16(Wg1, d + 32768 + 8192 + ldsw);
    async_lds16(Ag0 + 32, d + 16384 + ldsw);
    async_lds16(Ag1 + 32, d + 16384 + 8192 + ldsw);
    async_lds16(Wg0 + 32, d + 49152 + ldsw);
    async_lds16(Wg1 + 32, d + 49152 + 8192 + ldsw);
  }
  asm volatile("s_waitcnt vmcnt(4)" ::: "memory");  // Aks0,Bks0 of tile0 landed
  __builtin_amdgcn_s_barrier();

  for (int kt = 0; kt < NKT; ++kt) {
    const char* Ab = smem + ((kt & 1) << 16);
    const char* Bb = Ab + 32768;
    char* Sd = smem + (((kt + 1) & 1) << 16);
    const int kn = (kt + 1) << 6;  // next tile k-offset (elements)
    if (kt + 1 < NKT) {
      {  // ph1: ks0, C-half0; stage A-ks0(t+1)
        bf16x8 a[4], b[4];
        load_frags256<0, 0>(Ab, Bb, aoff, boff, a, b);
        async_lds16(Ag0 + kn, Sd + ldsw);
        async_lds16(Ag1 + kn, Sd + 8192 + ldsw);
        __builtin_amdgcn_s_barrier();
        __builtin_amdgcn_s_setprio(1);
        mfma256<0>(a, b, acc);
        __builtin_amdgcn_s_setprio(0);
        __builtin_amdgcn_sched_barrier(0);
        __builtin_amdgcn_s_barrier();
      }
      {  // ph2: ks0, C-half1; stage B-ks0(t+1); vmcnt(4)
        bf16x8 a[4], b[4];
        load_frags256<0, 1>(Ab, Bb, aoff, boff, a, b);
        async_lds16(Wg0 + kn, Sd + 32768 + ldsw);
        async_lds16(Wg1 + kn, Sd + 32768 + 8192 + ldsw);
        __builtin_amdgcn_s_barrier();
        __builtin_amdgcn_s_setprio(1);
        mfma256<1>(a, b, acc);
        __builtin_amdgcn_s_setprio(0);
        asm volatile("s_waitcnt vmcnt(4)" ::: "memory");
        __builtin_amdgcn_sched_barrier(0);
        __builtin_amdgcn_s_barrier();
      }
      {  // ph3: ks1, C-half0; stage A-ks1(t+1)
        bf16x8 a[4], b[4];
        load_frags256<1, 0>(Ab, Bb, aoff, boff, a, b);
        async_lds16(Ag0 + kn + 32, Sd + 16384 + ldsw);
        async_lds16(Ag1 + kn + 32, Sd + 16384 + 8192 + ldsw);
        __builtin_amdgcn_s_barrier();
        __builtin_amdgcn_s_setprio(1);
        mfma256<0>(a, b, acc);
        __builtin_amdgcn_s_setprio(0);
        __builtin_amdgcn_sched_barrier(0);
        __builtin_amdgcn_s_barrier();
      }
      {  // ph4: ks1, C-half1; stage B-ks1(t+1); vmcnt(4)
        bf16x8 a[4], b[4];
        load_frags256<1, 1>(Ab, Bb, aoff, boff, a, b);
        async_lds16(Wg0 + kn + 32, Sd + 49152 + ldsw);
        async_lds16(Wg1 + kn + 32, Sd + 49152 + 8192 + ldsw);
        __builtin_amdgcn_s_barrier();
        __builtin_amdgcn_s_setprio(1);
        mfma256<1>(a, b, acc);
        __builtin_amdgcn_s_setprio(0);
        asm volatile("s_waitcnt vmcnt(4)" ::: "memory");
        __builtin_amdgcn_sched_barrier(0);
        __builtin_amdgcn_s_barrier();
      }
    } else {  // last tile: no staging; ph2 must fully drain for ks1 reads
      {
        bf16x8 a[4], b[4];
        load_frags256<0, 0>(Ab, Bb, aoff, boff, a, b);
        __builtin_amdgcn_s_barrier();
        __builtin_amdgcn_s_setprio(1);
        mfma256<0>(a, b, acc);
        __builtin_amdgcn_s_setprio(0);
        __builtin_amdgcn_sched_barrier(0);
        __builtin_amdgcn_s_barrier();
      }
      {
        bf16x8 a[4], b[4];
        load_frags256<0, 1>(Ab, Bb, aoff, boff, a, b);
        __builtin_amdgcn_s_barrier();
        __builtin_amdgcn_s_setprio(1);
        mfma256<1>(a, b, acc);
        __builtin_amdgcn_s_setprio(0);
        asm volatile("s_waitcnt vmcnt(0)" ::: "memory");
        __builtin_amdgcn_sched_barrier(0);
        __builtin_amdgcn_s_barrier();
      }
      {
        bf16x8 a[4], b[4];
        load_frags256<1, 0>(Ab, Bb, aoff, boff, a, b);
        __builtin_amdgcn_s_barrier();
        __builtin_amdgcn_s_setprio(1);
        mfma256<0>(a, b, acc);
        __builtin_amdgcn_s_setprio(0);
        __builtin_amdgcn_sched_barrier(0);
        __builtin_amdgcn_s_barrier();
      }
      {
        bf16x8 a[4], b[4];
        load_frags256<1, 1>(Ab, Bb, aoff, boff, a, b);
        __builtin_amdgcn_s_barrier();
        __builtin_amdgcn_s_setprio(1);
        mfma256<1>(a, b, acc);
        __builtin_amdgcn_s_setprio(0);
      }
    }
  }

  // ---- epilogue ----
  if constexpr (EPI == 2) {
#pragma unroll
    for (int j = 0; j < 4; j++) {
      const int col = n0 + wc * 64 + j * 16 + l16;
      const float bv = b1[col];
#pragma unroll
      for (int mI = 0; mI < 8; mI++) {
        const int row = m0 + wr * 128 + mI * 16 + quad * 4;
#pragma unroll
        for (int r = 0; r < 4; r++) {
          o0[(size_t)(row + r) * NOUT + col] =
              __float2bfloat16(gelu_fast(acc[mI][j][r] + bv));
        }
      }
    }
  } else if constexpr (EPI == 3) {
    bf16* dst = (blockIdx.z == 0) ? o0
              : (blockIdx.z == 1) ? o1
              : (blockIdx.z == 2) ? o2 : o3;
#pragma unroll
    for (int j = 0; j < 4; j++) {
      const int col = n0 + wc * 64 + j * 16 + l16;
#pragma unroll
      for (int mI = 0; mI < 8; mI++) {
        const int row = m0 + wr * 128 + mI * 16 + quad * 4;
#pragma unroll
        for (int r = 0; r < 4; r++) {
          dst[(size_t)(row + r) * NOUT + col] = __float2bfloat16(acc[mI][j][r]);
        }
      }
    }
  } else {  // EPI == 4: QKV packed (segment-uniform per block)
    const int seg = n0 >> 10;  // 0=Q, 1=K, 2=V
#pragma unroll
    for (int j = 0; j < 4; j++) {
      const int col = n0 + wc * 64 + j * 16 + l16;
      const float bv = (seg == 0) ? b1[col]
                     : (seg == 1) ? b2[col - 1024] : b3[col - 2048];
      const int d = col & 63;
#pragma unroll
      for (int mI = 0; mI < 8; mI++) {
        const int row = m0 + wr * 128 + mI * 16 + quad * 4;
#pragma unroll
        for (int r = 0; r < 4; r++) {
          const int tok = row + r, n = tok & 1, l = tok >> 1;
          float v = acc[mI][j][r] + bv;
          if (seg == 0) {
            o0[(size_t)tok * 1024 + col] = __float2bfloat16(v * qscale);
          } else if (seg == 1) {
            const int h = (col - 1024) >> 6, hh = n * 16 + h;
            o2[((((size_t)hh * 32 + (l >> 6)) * 8 + (d >> 3)) * 64 + (l & 63)) * 8 +
               (d & 7)] = __float2bfloat16(v);
          } else {
            const int h = (col - 2048) >> 6, hh = n * 16 + h;
            o1[((((size_t)hh * 32 + (l >> 6)) * 8 + ((l >> 3) & 7)) * 64 + d) * 8 +
               (l & 7)] = __float2bfloat16(v);
          }
        }
      }
    }
  }
}

// ---------------------------------------------------------------------------
// Split-K4 reduce IN-PLACE on f32 out (which holds the residual):
//   out[i] = P0+P1+P2+P3 + bias[col] + out[i]
// ---------------------------------------------------------------------------
__global__ __launch_bounds__(256) void reduce4_kernel(
    const bf16* __restrict__ P0, const bf16* __restrict__ P1,
    const bf16* __restrict__ P2, const bf16* __restrict__ P3,
    const float* __restrict__ bias, float* __restrict__ out) {
  const int i = blockIdx.x * 256 + threadIdx.x;  // float4 index
  const size_t e0 = (size_t)i * 4;
  const int col = (int)(e0 & (E - 1));
  uint2 a0 = *(const uint2*)(P0 + e0);
  uint2 a1 = *(const uint2*)(P1 + e0);
  uint2 a2 = *(const uint2*)(P2 + e0);
  uint2 a3 = *(const uint2*)(P3 + e0);
  const bf16* q0 = (const bf16*)&a0;
  const bf16* q1 = (const bf16*)&a1;
  const bf16* q2 = (const bf16*)&a2;
  const bf16* q3 = (const bf16*)&a3;
  float4 b = *(const float4*)(bias + col);
  float4 r = *(const float4*)(out + e0);
  float4 o;
  o.x = (float)q0[0] + (float)q1[0] + (float)q2[0] + (float)q3[0] + b.x + r.x;
  o.y = (float)q0[1] + (float)q1[1] + (float)q2[1] + (float)q3[1] + b.y + r.y;
  o.z = (float)q0[2] + (float)q1[2] + (float)q2[2] + (float)q3[2] + b.z + r.z;
  o.w = (float)q0[3] + (float)q1[3] + (float)q2[3] + (float)q3[3] + b.w + r.w;
  *(float4*)(out + e0) = o;
}

// ---------------------------------------------------------------------------
// Fused out-proj reduce + LayerNorm2. One block per token.
// Writes the f32 residual to resout (= d_out, consumed in-place by reduce4).
// ---------------------------------------------------------------------------
__global__ __launch_bounds__(256) void redln_kernel(
    const bf16* __restrict__ P, const float* __restrict__ bias,
    const float* __restrict__ res, const float* __restrict__ wgt,
    const float* __restrict__ bia, float* __restrict__ resout,
    bf16* __restrict__ h2) {
  const int t = blockIdx.x, tid = threadIdx.x;
  const size_t base = (size_t)t * E;
  const int e0 = tid * 4;
  uint2 u0 = *(const uint2*)(P + base + e0);
  uint2 u1 = *(const uint2*)(P + (size_t)MT * E + base + e0);
  const bf16* p0 = (const bf16*)&u0;
  const bf16* p1 = (const bf16*)&u1;
  float4 b = *(const float4*)(bias + e0);
  float4 r = *(const float4*)(res + base + e0);
  float v4[4];
  v4[0] = (float)p0[0] + (float)p1[0] + b.x + r.x;
  v4[1] = (float)p0[1] + (float)p1[1] + b.y + r.y;
  v4[2] = (float)p0[2] + (float)p1[2] + b.z + r.z;
  v4[3] = (float)p0[3] + (float)p1[3] + b.w + r.w;
  *(float4*)(resout + base + e0) = *(float4*)v4;

  float s = 0.f, ss = 0.f;
#pragma unroll
  for (int i = 0; i < 4; i++) { s += v4[i]; ss += v4[i] * v4[i]; }
  for (int off = 32; off > 0; off >>= 1) {
    s += __shfl_down(s, off, 64);
    ss += __shfl_down(ss, off, 64);
  }
  __shared__ float rs[4], rss[4], mv[2];
  const int w = tid >> 6;
  if ((tid & 63) == 0) { rs[w] = s; rss[w] = ss; }
  __syncthreads();
  if (tid == 0) {
    float S = rs[0] + rs[1] + rs[2] + rs[3];
    float SS = rss[0] + rss[1] + rss[2] + rss[3];
    float mean = S * (1.f / E);
    float var = SS * (1.f / E) - mean * mean;
    mv[0] = mean; mv[1] = rsqrtf(var + 1e-5f);
  }
  __syncthreads();
  const float mean = mv[0], rstd = mv[1];
  float4 wg = *(const float4*)(wgt + e0);
  float4 bb = *(const float4*)(bia + e0);
  bf16 o4[4];
  o4[0] = __float2bfloat16((v4[0] - mean) * rstd * wg.x + bb.x);
  o4[1] = __float2bfloat16((v4[1] - mean) * rstd * wg.y + bb.y);
  o4[2] = __float2bfloat16((v4[2] - mean) * rstd * wg.z + bb.z);
  o4[3] = __float2bfloat16((v4[3] - mean) * rstd * wg.w + bb.w);
  *(uint2*)(h2 + base + e0) = *(uint2*)o4;
}

// ---------------------------------------------------------------------------
// LayerNorm over E=1024 per token (f32 in, bf16 out). One block per token.
// ---------------------------------------------------------------------------
__global__ __launch_bounds__(256) void ln_kernel(
    const float* __restrict__ x, const float* __restrict__ wgt,
    const float* __restrict__ bia, bf16* __restrict__ out) {
  const int t = blockIdx.x, tid = threadIdx.x;
  const size_t base = (size_t)t * E;
  float v4[4], s = 0.f, ss = 0.f;
#pragma unroll
  for (int i = 0; i < 4; i++) {
    float v = x[base + i * 256 + tid];
    v4[i] = v; s += v; ss += v * v;
  }
  for (int off = 32; off > 0; off >>= 1) {
    s += __shfl_down(s, off, 64);
    ss += __shfl_down(ss, off, 64);
  }
  __shared__ float rs[4], rss[4], mv[2];
  const int w = tid >> 6;
  if ((tid & 63) == 0) { rs[w] = s; rss[w] = ss; }
  __syncthreads();
  if (tid == 0) {
    float S = rs[0] + rs[1] + rs[2] + rs[3];
    float SS = rss[0] + rss[1] + rss[2] + rss[3];
    float mean = S * (1.f / E);
    float var = SS * (1.f / E) - mean * mean;
    mv[0] = mean; mv[1] = rsqrtf(var + 1e-5f);
  }
  __syncthreads();
  const float mean = mv[0], rstd = mv[1];
#pragma unroll
  for (int i = 0; i < 4; i++) {
    const int e = i * 256 + tid;
    float r = (v4[i] - mean) * rstd * wgt[e] + bia[e];
    out[base + e] = __float2bfloat16(r);
  }
}

// ---------------------------------------------------------------------------
// Flash attention v11: dbuf + counted vmcnt + coalesced staging from packed
// K/V (KT/VT are byte-identical to the KB/VB LDS images). R3-verified.
// ---------------------------------------------------------------------------
__global__ __launch_bounds__(256) void attn_kernel(
    const bf16* __restrict__ Q1, const bf16* __restrict__ KT,
    const bf16* __restrict__ VT, bf16* __restrict__ O) {
  __shared__ __align__(16) bf16 KB[2][512 * 8];  // 2 x 8 KB
  __shared__ __align__(16) bf16 VB[2][512 * 8];  // 2 x 8 KB
  const int tid = threadIdx.x;
  const int w = tid >> 6, lane = tid & 63, quad = lane >> 4, l16 = lane & 15;
  const int bid = blockIdx.x;          // 0..1023
  const int x = bid & 7;
  const int m = (bid >> 3) & 31;
  const int g = bid >> 8;              // 0..3
  const int j = m >> 2;                // 0..7
  const int hh = (m & 3) * 8 + x;      // 0..31
  const int qt = (g == 0) ? j : (g == 1) ? (31 - j) : (g == 2) ? (j + 8) : (23 - j);
  const int n = hh >> 4, h = hh & 15;

  const bf16* Qp = Q1 + n * E + h * Dd;                    // row stride 1024? no: 2048 tok-major
  const bf16* Kb = KT + (size_t)hh * 32 * 4096;            // 8KB per k-tile
  const bf16* Vb = VT + (size_t)hh * 32 * 4096;
  const int so = w * 512 + lane * 8;  // per-lane staging src offset (elems)

  const int ql = qt * 64 + w * 16 + l16;
  const bf16x8 aq0 = ld8(Qp + (size_t)ql * 2048 + quad * 8);
  const bf16x8 aq1 = ld8(Qp + (size_t)ql * 2048 + 32 + quad * 8);
  // Drain Q loads once so the loop's vmcnt ledger counts staging loads only.
  asm volatile("s_waitcnt vmcnt(0)" ::: "memory");

  // prologue: stage tile 0 -> buf 0 (coalesced 1KB chunks)
  async_lds16(Kb + so, &KB[0][w * 512]);
  async_lds16(Kb + 2048 + so, &KB[0][2048 + w * 512]);
  async_lds16(Vb + so, &VB[0][w * 512]);
  async_lds16(Vb + 2048 + so, &VB[0][2048 + w * 512]);

  f32x4 o_acc[4];
#pragma unroll
  for (int d = 0; d < 4; d++)
#pragma unroll
    for (int r = 0; r < 4; r++) o_acc[d][r] = 0.f;
  float m_run = -3e30f, l_run = 0.f;

  for (int kt = 0; kt <= qt; ++kt) {
    const bf16* KBb = KB[kt & 1];
    const bf16* VBb = VB[kt & 1];
    if (kt < qt) {
      const size_t tb = (size_t)(kt + 1) * 4096;
      bf16* Kd = &KB[(kt & 1) ^ 1][0];
      bf16* Vd = &VB[(kt & 1) ^ 1][0];
      async_lds16(Kb + tb + so, Kd + w * 512);
      async_lds16(Kb + tb + 2048 + so, Kd + 2048 + w * 512);
      async_lds16(Vb + tb + so, Vd + w * 512);
      async_lds16(Vb + tb + 2048 + so, Vd + 2048 + w * 512);
      asm volatile("s_waitcnt vmcnt(4)" ::: "memory");
    } else {
      asm volatile("s_waitcnt vmcnt(0)" ::: "memory");
    }
    __builtin_amdgcn_s_barrier();

    // ---- QK^T ----
    f32x4 s[4];
    __builtin_amdgcn_s_setprio(1);
#pragma unroll
    for (int ks = 0; ks < 4; ks++) {
      const bf16x8 kc0 = ld8(&KBb[(size_t)((quad)*64 + ks * 16 + l16) * 8]);
      const bf16x8 kc1 = ld8(&KBb[(size_t)((4 + quad) * 64 + ks * 16 + l16) * 8]);
#pragma unroll
      for (int r = 0; r < 4; r++) s[ks][r] = 0.f;
      s[ks] = __builtin_amdgcn_mfma_f32_16x16x32_bf16(kc0, aq0, s[ks], 0, 0, 0);
      s[ks] = __builtin_amdgcn_mfma_f32_16x16x32_bf16(kc1, aq1, s[ks], 0, 0, 0);
    }
    __builtin_amdgcn_s_setprio(0);

    if (kt == qt) {
#pragma unroll
      for (int ks = 0; ks < 4; ks++) {
#pragma unroll
        for (int r = 0; r < 4; r++) {
          const int kg = kt * 64 + ks * 16 + quad * 4 + r;
          if (kg > ql) s[ks][r] = -14427.0f;
        }
      }
    }

    // ---- online softmax (defer-max, THR=8 in exp2 domain) ----
    float tmax = s[0][0];
#pragma unroll
    for (int ks = 0; ks < 4; ks++)
#pragma unroll
      for (int r = 0; r < 4; r++) tmax = fmaxf(tmax, s[ks][r]);
    tmax = fmaxf(tmax, __shfl_xor(tmax, 16, 64));
    tmax = fmaxf(tmax, __shfl_xor(tmax, 32, 64));
    float mbase = m_run;
    if (__any(tmax - m_run > 8.0f)) {  // wave-uniform branch
      const float mnew = fmaxf(m_run, tmax);
      const float alpha = exp2f(m_run - mnew);
      m_run = mnew;
      mbase = mnew;
      l_run *= alpha;
#pragma unroll
      for (int d = 0; d < 4; d++)
#pragma unroll
        for (int r = 0; r < 4; r++) o_acc[d][r] *= alpha;
    }
    float rsum = 0.f;
    short4v pf[4];
#pragma unroll
    for (int ks = 0; ks < 4; ks++) {
#pragma unroll
      for (int r = 0; r < 4; r++) {
        const float pv = exp2f(s[ks][r] - mbase);
        rsum += pv;
        pf[ks][r] = bfbits(pv);
      }
    }
    rsum += __shfl_xor(rsum, 16, 64);
    rsum += __shfl_xor(rsum, 32, 64);
    l_run += rsum;

    // ---- PV ----
    __builtin_amdgcn_s_setprio(1);
#pragma unroll
    for (int d = 0; d < 4; d++) {
#pragma unroll
      for (int ks = 0; ks < 4; ks++) {
        const int gg = ks * 2 + (quad >> 1);
        const short4v av =
            *(const short4v*)&VBb[(size_t)(gg * 64 + d * 16 + l16) * 8 + (quad & 1) * 4];
        o_acc[d] = __builtin_amdgcn_mfma_f32_16x16x16bf16_1k(av, pf[ks], o_acc[d], 0, 0, 0);
      }
    }
    __builtin_amdgcn_s_setprio(0);

    __builtin_amdgcn_sched_barrier(0);
    __builtin_amdgcn_s_barrier();
  }

  const float inv_l = 1.f / fmaxf(l_run, 1e-30f);
  const size_t obase = (size_t)ql * (Nb * E) + (size_t)n * E + h * Dd;
#pragma unroll
  for (int d = 0; d < 4; d++)
#pragma unroll
    for (int r = 0; r < 4; r++)
      O[obase + d * 16 + quad * 4 + r] = __float2bfloat16(o_acc[d][r] * inv_l);
}

// ---------------------------------------------------------------------------
extern "C" void kernel_launch(void* const* d_in, const int* in_sizes, int n_in,
                              void* d_out, int out_size, void* d_ws, size_t ws_size,
                              hipStream_t stream) {
  const float* x    = (const float*)d_in[0];
  const float* ln1w = (const float*)d_in[1];
  const float* ln1b = (const float*)d_in[2];
  const float* wq   = (const float*)d_in[3];
  const float* bq   = (const float*)d_in[4];
  const float* wk   = (const float*)d_in[5];
  const float* bk   = (const float*)d_in[6];
  const float* wv   = (const float*)d_in[7];
  const float* bv   = (const float*)d_in[8];
  const float* wout = (const float*)d_in[9];
  const float* bout = (const float*)d_in[10];
  const float* ln2w = (const float*)d_in[11];
  const float* ln2b = (const float*)d_in[12];
  const float* fc1w = (const float*)d_in[13];
  const float* fc1b = (const float*)d_in[14];
  const float* fc2w = (const float*)d_in[15];
  const float* fc2b = (const float*)d_in[16];

  char* ws = (char*)d_ws;
  bf16* wqkvb = (bf16*)(ws);                        // 0-6 MB  [wq;wk;wv]
  bf16* woutb = (bf16*)(ws + ((size_t)6 << 20));    // 6-8 MB
  bf16* f1wb  = (bf16*)(ws + ((size_t)8 << 20));    // 8-16 MB
  bf16* f2wb  = (bf16*)(ws + ((size_t)16 << 20));   // 16-24 MB
  bf16* h1    = (bf16*)(ws + ((size_t)24 << 20));   // 24-32 MB (h2 reuses)
  bf16* qk1   = (bf16*)(ws + ((size_t)32 << 20));   // 32-40 MB Q [4096][1024]
  bf16* ktg   = (bf16*)(ws + ((size_t)40 << 20));   // 40-48 MB K packed
  bf16* vtg   = (bf16*)(ws + ((size_t)48 << 20));   // 48-56 MB V packed
  bf16* o     = (bf16*)(ws + ((size_t)56 << 20));   // 56-64 MB
  bf16* Pout  = (bf16*)(ws + ((size_t)32 << 20));   // 32-48: out-proj splitK (qk1/ktg dead)
  bf16* f1    = (bf16*)(ws + ((size_t)32 << 20));   // 32-64 (qk1,ktg,vtg,o dead)
  bf16* h2    = h1;
  // FC2 split-K4 partials (8 MB each), lifetimes checked:
  bf16* FP0   = (bf16*)(ws);                        // wqkvb/woutb dead after out-proj
  bf16* FP1   = (bf16*)(ws + ((size_t)8 << 20));    // f1wb dead after FC1
  bf16* FP2   = (bf16*)(ws + ((size_t)64 << 20));   // 64-72 free (x1 eliminated)
  bf16* FP3   = (bf16*)(ws + ((size_t)72 << 20));   // 72-80 free
  float* outp = (float*)d_out;                      // holds f32 residual, then final

  static bool g_shmem_attr = false;
  if (!g_shmem_attr) {
    hipFuncSetAttribute(reinterpret_cast<const void*>(gemm256<1024, 1024, 3072, 4>),
                        hipFuncAttributeMaxDynamicSharedMemorySize, 131072);
    hipFuncSetAttribute(reinterpret_cast<const void*>(gemm256<512, 1024, 1024, 3>),
                        hipFuncAttributeMaxDynamicSharedMemorySize, 131072);
    hipFuncSetAttribute(reinterpret_cast<const void*>(gemm256<1024, 1024, 4096, 2>),
                        hipFuncAttributeMaxDynamicSharedMemorySize, 131072);
    hipFuncSetAttribute(reinterpret_cast<const void*>(gemm256<1024, 4096, 1024, 3>),
                        hipFuncAttributeMaxDynamicSharedMemorySize, 131072);
    g_shmem_attr = true;
  }

  cvt_all_kernel<<<12288, 256, 0, stream>>>(wq, wk, wv, wout, fc1w, fc2w,
                                            wqkvb, woutb, f1wb, f2wb);

  ln_kernel<<<MT, 256, 0, stream>>>(x, ln1w, ln1b, h1);

  // QKV: 256x256 8-phase, packed epilogue. q pre-scale folded with log2(e).
  gemm256<1024, 1024, 3072, 4><<<dim3(12, 16), 512, 131072, stream>>>(
      h1, wqkvb, bq, bk, bv, 0.125f * 1.44269504f, qk1, vtg, ktg, nullptr);

  attn_kernel<<<1024, 256, 0, stream>>>(qk1, ktg, vtg, o);

  // out-proj: split-K2 partials into Pout / Pout+MT*E
  gemm256<512, 1024, 1024, 3><<<dim3(4, 16, 2), 512, 131072, stream>>>(
      o, woutb, nullptr, nullptr, nullptr, 1.f,
      Pout, Pout + (size_t)MT * E, nullptr, nullptr);
  redln_kernel<<<MT, 256, 0, stream>>>(Pout, bout, x, ln2w, ln2b, outp, h2);

  // FC1: gelu epilogue
  gemm256<1024, 1024, 4096, 2><<<dim3(Ff / 256, MT / 256), 512, 131072, stream>>>(
      h2, f1wb, fc1b, nullptr, nullptr, 1.f, f1, nullptr, nullptr, nullptr);

  // FC2: split-K4 (256 blocks = 1/CU)
  gemm256<1024, 4096, 1024, 3><<<dim3(4, 16, 4), 512, 131072, stream>>>(
      f1, f2wb, nullptr, nullptr, nullptr, 1.f, FP0, FP1, FP2, FP3);
  reduce4_kernel<<<MT * E / 1024, 256, 0, stream>>>(FP0, FP1, FP2, FP3, fc2b, outp);
}

// Round 5
// 344.985 us; speedup vs baseline: 1.0769x; 1.0650x over previous
//
#include <hip/hip_runtime.h>
#include <hip/hip_bf16.h>
#include <math.h>

using bf16 = __hip_bfloat16;
typedef __bf16 bf16x8 __attribute__((ext_vector_type(8)));
typedef short  short4v __attribute__((ext_vector_type(4)));
typedef float  f32x4  __attribute__((ext_vector_type(4)));

static constexpr int Lq = 2048, Nb = 2, E = 1024, Hh = 16, Dd = 64, Ff = 4096;
static constexpr int MT = Lq * Nb;          // 4096 tokens

__device__ __forceinline__ void async_lds16(const void* g, void* l) {
  __builtin_amdgcn_global_load_lds(
      (const __attribute__((address_space(1))) void*)g,
      (__attribute__((address_space(3))) void*)l, 16, 0, 0);
}
__device__ __forceinline__ bf16x8 ld8(const bf16* p) { return *(const bf16x8*)p; }
__device__ __forceinline__ short bfbits(float x) {
  bf16 t = __float2bfloat16(x);
  return *(short*)&t;
}
// fast gelu (tanh form, reduced): gelu(v) = v * t/(t+1)
__device__ __forceinline__ float gelu_fast(float v) {
  const float y = fminf(2.302208f * (v + 0.044715f * v * v * v), 80.f);
  const float t = exp2f(y);
  return v * t / (t + 1.0f);
}

// ---------------------------------------------------------------------------
// Fused f32 -> bf16 cast of all 6 weight matrices in ONE dispatch.
// ---------------------------------------------------------------------------
__global__ __launch_bounds__(256) void cvt_all_kernel(
    const float* __restrict__ wq, const float* __restrict__ wk,
    const float* __restrict__ wv, const float* __restrict__ wout,
    const float* __restrict__ fc1w, const float* __restrict__ fc2w,
    bf16* __restrict__ wqkvb, bf16* __restrict__ woutb,
    bf16* __restrict__ f1wb, bf16* __restrict__ f2wb) {
  const int i = blockIdx.x * 256 + threadIdx.x;
  const float* src;
  bf16* dst;
  size_t off;
  if (i < 786432) {            // qkv: three E*E blocks concat in wqkvb
    const int r = i >> 18;     // 0,1,2
    off = (size_t)(i & 262143);
    src = (r == 0) ? wq : (r == 1) ? wk : wv;
    dst = wqkvb + (size_t)r * (E * E);
  } else if (i < 1048576) {
    off = (size_t)(i - 786432); src = wout; dst = woutb;
  } else if (i < 2097152) {
    off = (size_t)(i - 1048576); src = fc1w; dst = f1wb;
  } else {
    off = (size_t)(i - 2097152); src = fc2w; dst = f2wb;
  }
  float4 v = ((const float4*)src)[off];
  bf16 o4[4] = {__float2bfloat16(v.x), __float2bfloat16(v.y),
                __float2bfloat16(v.z), __float2bfloat16(v.w)};
  *(uint2*)(dst + 4 * off) = *(uint2*)o4;
}

// ---------------------------------------------------------------------------
// 128x256-tile GEMM, BK=32, 8 waves (2M x 4N wave grid, per-wave C = 64x64),
// 48 KB double-buffered LDS -> 2 blocks/CU (16 waves/CU, 4/SIMD): TLP-robust.
// Counted-vmcnt double buffer (attn-v11-verified ledger):
//   iter kt: stage tile kt+1 (3 x global_load_lds / thread) into buf kt^1,
//            vmcnt(3) drains OWN tile-kt loads, barrier (all waves drained
//            theirs -> LDS image complete), ds_read + 16 MFMA, barrier
//            (reads done before next iter's stage overwrites buf).
// LDS swizzle (gemm256-verified, 0 conflicts): 16B chunk c of row r stored at
//   chunk c ^ ((r>>1)&3); staging source pre-inverse-swizzled; frag read
//   offset simplifies to kq = (quad ^ ((l16>>1)&3))*8 (wave-uniform rows
//   mod 16 cancel).
// EPI 2: gelu(acc + b1[col]) -> bf16 o0[row][NOUT]
// EPI 3: bf16 partial -> {o0..o3}[blockIdx.z][row][NOUT]  (split-K)
// EPI 4: QKV packed (R3-verified layouts):
//   seg0: Q (acc+b)*qscale -> o0[tok][1024]
//   seg1: K -> o2[hh][l>>6][d>>3][l&63][d&7]
//   seg2: V -> o1[hh][l>>6][(l>>3)&7][d][l&7]
// ---------------------------------------------------------------------------
template <int K, int KSTR, int NOUT, int EPI>
__global__ __launch_bounds__(512, 4) void gemm_tlp(
    const bf16* __restrict__ A, const bf16* __restrict__ W,
    const float* __restrict__ b1, const float* __restrict__ b2,
    const float* __restrict__ b3, float qscale,
    bf16* __restrict__ o0, bf16* __restrict__ o1,
    bf16* __restrict__ o2, bf16* __restrict__ o3) {
  // per buf: A 128x32 = 4096 elems | B 256x32 = 8192 elems  (24 KB)
  __shared__ __align__(16) bf16 sm[2][12288];
  constexpr int NKT = K / 32;
  static_assert(NKT >= 2, "need >=2 K-tiles");
  const int tid = threadIdx.x;
  const int w = tid >> 6, lane = tid & 63;
  const int quad = lane >> 4, l16 = lane & 15;
  const int wm = (w >> 2) * 64, wn = (w & 3) * 64;
  const int m0 = blockIdx.y * 128, n0 = blockIdx.x * 256;
  const int koff = blockIdx.z * K;

  // staging: thread stages 3 chunks (1 A-row chunk + 2 B-row chunks).
  // dest linear: A: elem tid*8; B: 4096+tid*8 (rows 0-127), 8192+tid*8
  // (rows 128-255). Source col pre-inverse-swizzled. Note (128+srow)>>1
  // keeps the same &3 as srow>>1 (128 is a multiple of 8), so one sca works.
  const int srow = tid >> 2;
  const int sca = ((tid & 3) ^ ((srow >> 1) & 3)) * 8;
  const bf16* Asrc = A + (size_t)(m0 + srow) * KSTR + koff + sca;
  const bf16* Wsrc0 = W + (size_t)(n0 + srow) * KSTR + koff + sca;
  const bf16* Wsrc1 = W + (size_t)(n0 + 128 + srow) * KSTR + koff + sca;
  const int d8 = tid * 8;

  // fragment read swizzle: rows differ by multiples of 16 -> (row>>1)&3
  // depends only on l16.
  const int kq = ((quad ^ ((l16 >> 1) & 3)) << 3);

  f32x4 acc[4][4];
#pragma unroll
  for (int i = 0; i < 4; i++)
#pragma unroll
    for (int j = 0; j < 4; j++)
#pragma unroll
      for (int r = 0; r < 4; r++) acc[i][j][r] = 0.f;

  // prologue: stage tile 0 -> buf 0
  async_lds16(Asrc, &sm[0][d8]);
  async_lds16(Wsrc0, &sm[0][4096 + d8]);
  async_lds16(Wsrc1, &sm[0][8192 + d8]);

  for (int kt = 0; kt < NKT; ++kt) {
    const bf16* S = sm[kt & 1];
    if (kt + 1 < NKT) {
      const int kn = (kt + 1) * 32;
      bf16* D = sm[(kt & 1) ^ 1];
      async_lds16(Asrc + kn, &D[d8]);
      async_lds16(Wsrc0 + kn, &D[4096 + d8]);
      async_lds16(Wsrc1 + kn, &D[8192 + d8]);
      asm volatile("s_waitcnt vmcnt(3)" ::: "memory");
    } else {
      asm volatile("s_waitcnt vmcnt(0)" ::: "memory");
    }
    __builtin_amdgcn_s_barrier();

    bf16x8 a[4], b[4];
#pragma unroll
    for (int i = 0; i < 4; i++)
      a[i] = ld8(&S[(wm + i * 16 + l16) * 32 + kq]);
#pragma unroll
    for (int j = 0; j < 4; j++)
      b[j] = ld8(&S[4096 + (wn + j * 16 + l16) * 32 + kq]);

    __builtin_amdgcn_s_setprio(1);
#pragma unroll
    for (int i = 0; i < 4; i++)
#pragma unroll
      for (int j = 0; j < 4; j++)
        acc[i][j] = __builtin_amdgcn_mfma_f32_16x16x32_bf16(a[i], b[j], acc[i][j], 0, 0, 0);
    __builtin_amdgcn_s_setprio(0);
    __builtin_amdgcn_sched_barrier(0);
    __builtin_amdgcn_s_barrier();
  }

  // ---- epilogue ----
  if constexpr (EPI == 2) {
#pragma unroll
    for (int j = 0; j < 4; j++) {
      const int col = n0 + wn + j * 16 + l16;
      const float bv = b1[col];
#pragma unroll
      for (int i = 0; i < 4; i++) {
        const int row = m0 + wm + i * 16 + quad * 4;
#pragma unroll
        for (int r = 0; r < 4; r++) {
          o0[(size_t)(row + r) * NOUT + col] =
              __float2bfloat16(gelu_fast(acc[i][j][r] + bv));
        }
      }
    }
  } else if constexpr (EPI == 3) {
    bf16* dst = (blockIdx.z == 0) ? o0
              : (blockIdx.z == 1) ? o1
              : (blockIdx.z == 2) ? o2 : o3;
#pragma unroll
    for (int j = 0; j < 4; j++) {
      const int col = n0 + wn + j * 16 + l16;
#pragma unroll
      for (int i = 0; i < 4; i++) {
        const int row = m0 + wm + i * 16 + quad * 4;
#pragma unroll
        for (int r = 0; r < 4; r++) {
          dst[(size_t)(row + r) * NOUT + col] = __float2bfloat16(acc[i][j][r]);
        }
      }
    }
  } else {  // EPI == 4: QKV packed (segment-uniform per block)
    const int seg = n0 >> 10;  // 0=Q, 1=K, 2=V
#pragma unroll
    for (int j = 0; j < 4; j++) {
      const int col = n0 + wn + j * 16 + l16;
      const float bv = (seg == 0) ? b1[col]
                     : (seg == 1) ? b2[col - 1024] : b3[col - 2048];
      const int d = col & 63;
#pragma unroll
      for (int i = 0; i < 4; i++) {
        const int row = m0 + wm + i * 16 + quad * 4;
#pragma unroll
        for (int r = 0; r < 4; r++) {
          const int tok = row + r, n = tok & 1, l = tok >> 1;
          float v = acc[i][j][r] + bv;
          if (seg == 0) {
            o0[(size_t)tok * 1024 + col] = __float2bfloat16(v * qscale);
          } else if (seg == 1) {
            const int h = (col - 1024) >> 6, hh = n * 16 + h;
            o2[((((size_t)hh * 32 + (l >> 6)) * 8 + (d >> 3)) * 64 + (l & 63)) * 8 +
               (d & 7)] = __float2bfloat16(v);
          } else {
            const int h = (col - 2048) >> 6, hh = n * 16 + h;
            o1[((((size_t)hh * 32 + (l >> 6)) * 8 + ((l >> 3) & 7)) * 64 + d) * 8 +
               (l & 7)] = __float2bfloat16(v);
          }
        }
      }
    }
  }
}

// ---------------------------------------------------------------------------
// Split-K4 reduce IN-PLACE on f32 out (which holds the residual):
//   out[i] = P0+P1+P2+P3 + bias[col] + out[i]
// ---------------------------------------------------------------------------
__global__ __launch_bounds__(256) void reduce4_kernel(
    const bf16* __restrict__ P0, const bf16* __restrict__ P1,
    const bf16* __restrict__ P2, const bf16* __restrict__ P3,
    const float* __restrict__ bias, float* __restrict__ out) {
  const int i = blockIdx.x * 256 + threadIdx.x;  // float4 index
  const size_t e0 = (size_t)i * 4;
  const int col = (int)(e0 & (E - 1));
  uint2 a0 = *(const uint2*)(P0 + e0);
  uint2 a1 = *(const uint2*)(P1 + e0);
  uint2 a2 = *(const uint2*)(P2 + e0);
  uint2 a3 = *(const uint2*)(P3 + e0);
  const bf16* q0 = (const bf16*)&a0;
  const bf16* q1 = (const bf16*)&a1;
  const bf16* q2 = (const bf16*)&a2;
  const bf16* q3 = (const bf16*)&a3;
  float4 b = *(const float4*)(bias + col);
  float4 r = *(const float4*)(out + e0);
  float4 o;
  o.x = (float)q0[0] + (float)q1[0] + (float)q2[0] + (float)q3[0] + b.x + r.x;
  o.y = (float)q0[1] + (float)q1[1] + (float)q2[1] + (float)q3[1] + b.y + r.y;
  o.z = (float)q0[2] + (float)q1[2] + (float)q2[2] + (float)q3[2] + b.z + r.z;
  o.w = (float)q0[3] + (float)q1[3] + (float)q2[3] + (float)q3[3] + b.w + r.w;
  *(float4*)(out + e0) = o;
}

// ---------------------------------------------------------------------------
// Fused out-proj reduce + LayerNorm2. One block per token.
// Writes the f32 residual to resout (= d_out, consumed in-place by reduce4).
// ---------------------------------------------------------------------------
__global__ __launch_bounds__(256) void redln_kernel(
    const bf16* __restrict__ P, const float* __restrict__ bias,
    const float* __restrict__ res, const float* __restrict__ wgt,
    const float* __restrict__ bia, float* __restrict__ resout,
    bf16* __restrict__ h2) {
  const int t = blockIdx.x, tid = threadIdx.x;
  const size_t base = (size_t)t * E;
  const int e0 = tid * 4;
  uint2 u0 = *(const uint2*)(P + base + e0);
  uint2 u1 = *(const uint2*)(P + (size_t)MT * E + base + e0);
  const bf16* p0 = (const bf16*)&u0;
  const bf16* p1 = (const bf16*)&u1;
  float4 b = *(const float4*)(bias + e0);
  float4 r = *(const float4*)(res + base + e0);
  float v4[4];
  v4[0] = (float)p0[0] + (float)p1[0] + b.x + r.x;
  v4[1] = (float)p0[1] + (float)p1[1] + b.y + r.y;
  v4[2] = (float)p0[2] + (float)p1[2] + b.z + r.z;
  v4[3] = (float)p0[3] + (float)p1[3] + b.w + r.w;
  *(float4*)(resout + base + e0) = *(float4*)v4;

  float s = 0.f, ss = 0.f;
#pragma unroll
  for (int i = 0; i < 4; i++) { s += v4[i]; ss += v4[i] * v4[i]; }
  for (int off = 32; off > 0; off >>= 1) {
    s += __shfl_down(s, off, 64);
    ss += __shfl_down(ss, off, 64);
  }
  __shared__ float rs[4], rss[4], mv[2];
  const int w = tid >> 6;
  if ((tid & 63) == 0) { rs[w] = s; rss[w] = ss; }
  __syncthreads();
  if (tid == 0) {
    float S = rs[0] + rs[1] + rs[2] + rs[3];
    float SS = rss[0] + rss[1] + rss[2] + rss[3];
    float mean = S * (1.f / E);
    float var = SS * (1.f / E) - mean * mean;
    mv[0] = mean; mv[1] = rsqrtf(var + 1e-5f);
  }
  __syncthreads();
  const float mean = mv[0], rstd = mv[1];
  float4 wg = *(const float4*)(wgt + e0);
  float4 bb = *(const float4*)(bia + e0);
  bf16 o4[4];
  o4[0] = __float2bfloat16((v4[0] - mean) * rstd * wg.x + bb.x);
  o4[1] = __float2bfloat16((v4[1] - mean) * rstd * wg.y + bb.y);
  o4[2] = __float2bfloat16((v4[2] - mean) * rstd * wg.z + bb.z);
  o4[3] = __float2bfloat16((v4[3] - mean) * rstd * wg.w + bb.w);
  *(uint2*)(h2 + base + e0) = *(uint2*)o4;
}

// ---------------------------------------------------------------------------
// LayerNorm over E=1024 per token (f32 in, bf16 out). One block per token.
// ---------------------------------------------------------------------------
__global__ __launch_bounds__(256) void ln_kernel(
    const float* __restrict__ x, const float* __restrict__ wgt,
    const float* __restrict__ bia, bf16* __restrict__ out) {
  const int t = blockIdx.x, tid = threadIdx.x;
  const size_t base = (size_t)t * E;
  float v4[4], s = 0.f, ss = 0.f;
#pragma unroll
  for (int i = 0; i < 4; i++) {
    float v = x[base + i * 256 + tid];
    v4[i] = v; s += v; ss += v * v;
  }
  for (int off = 32; off > 0; off >>= 1) {
    s += __shfl_down(s, off, 64);
    ss += __shfl_down(ss, off, 64);
  }
  __shared__ float rs[4], rss[4], mv[2];
  const int w = tid >> 6;
  if ((tid & 63) == 0) { rs[w] = s; rss[w] = ss; }
  __syncthreads();
  if (tid == 0) {
    float S = rs[0] + rs[1] + rs[2] + rs[3];
    float SS = rss[0] + rss[1] + rss[2] + rss[3];
    float mean = S * (1.f / E);
    float var = SS * (1.f / E) - mean * mean;
    mv[0] = mean; mv[1] = rsqrtf(var + 1e-5f);
  }
  __syncthreads();
  const float mean = mv[0], rstd = mv[1];
#pragma unroll
  for (int i = 0; i < 4; i++) {
    const int e = i * 256 + tid;
    float r = (v4[i] - mean) * rstd * wgt[e] + bia[e];
    out[base + e] = __float2bfloat16(r);
  }
}

// ---------------------------------------------------------------------------
// Flash attention v11: dbuf + counted vmcnt + coalesced staging from packed
// K/V (KT/VT are byte-identical to the KB/VB LDS images). R3-verified.
// ---------------------------------------------------------------------------
__global__ __launch_bounds__(256) void attn_kernel(
    const bf16* __restrict__ Q1, const bf16* __restrict__ KT,
    const bf16* __restrict__ VT, bf16* __restrict__ O) {
  __shared__ __align__(16) bf16 KB[2][512 * 8];  // 2 x 8 KB
  __shared__ __align__(16) bf16 VB[2][512 * 8];  // 2 x 8 KB
  const int tid = threadIdx.x;
  const int w = tid >> 6, lane = tid & 63, quad = lane >> 4, l16 = lane & 15;
  const int bid = blockIdx.x;          // 0..1023
  const int x = bid & 7;
  const int m = (bid >> 3) & 31;
  const int g = bid >> 8;              // 0..3
  const int j = m >> 2;                // 0..7
  const int hh = (m & 3) * 8 + x;      // 0..31
  const int qt = (g == 0) ? j : (g == 1) ? (31 - j) : (g == 2) ? (j + 8) : (23 - j);
  const int n = hh >> 4, h = hh & 15;

  const bf16* Qp = Q1 + n * E + h * Dd;
  const bf16* Kb = KT + (size_t)hh * 32 * 4096;            // 8KB per k-tile
  const bf16* Vb = VT + (size_t)hh * 32 * 4096;
  const int so = w * 512 + lane * 8;  // per-lane staging src offset (elems)

  const int ql = qt * 64 + w * 16 + l16;
  const bf16x8 aq0 = ld8(Qp + (size_t)ql * 2048 + quad * 8);
  const bf16x8 aq1 = ld8(Qp + (size_t)ql * 2048 + 32 + quad * 8);
  // Drain Q loads once so the loop's vmcnt ledger counts staging loads only.
  asm volatile("s_waitcnt vmcnt(0)" ::: "memory");

  // prologue: stage tile 0 -> buf 0 (coalesced 1KB chunks)
  async_lds16(Kb + so, &KB[0][w * 512]);
  async_lds16(Kb + 2048 + so, &KB[0][2048 + w * 512]);
  async_lds16(Vb + so, &VB[0][w * 512]);
  async_lds16(Vb + 2048 + so, &VB[0][2048 + w * 512]);

  f32x4 o_acc[4];
#pragma unroll
  for (int d = 0; d < 4; d++)
#pragma unroll
    for (int r = 0; r < 4; r++) o_acc[d][r] = 0.f;
  float m_run = -3e30f, l_run = 0.f;

  for (int kt = 0; kt <= qt; ++kt) {
    const bf16* KBb = KB[kt & 1];
    const bf16* VBb = VB[kt & 1];
    if (kt < qt) {
      const size_t tb = (size_t)(kt + 1) * 4096;
      bf16* Kd = &KB[(kt & 1) ^ 1][0];
      bf16* Vd = &VB[(kt & 1) ^ 1][0];
      async_lds16(Kb + tb + so, Kd + w * 512);
      async_lds16(Kb + tb + 2048 + so, Kd + 2048 + w * 512);
      async_lds16(Vb + tb + so, Vd + w * 512);
      async_lds16(Vb + tb + 2048 + so, Vd + 2048 + w * 512);
      asm volatile("s_waitcnt vmcnt(4)" ::: "memory");
    } else {
      asm volatile("s_waitcnt vmcnt(0)" ::: "memory");
    }
    __builtin_amdgcn_s_barrier();

    // ---- QK^T ----
    f32x4 s[4];
    __builtin_amdgcn_s_setprio(1);
#pragma unroll
    for (int ks = 0; ks < 4; ks++) {
      const bf16x8 kc0 = ld8(&KBb[(size_t)((quad)*64 + ks * 16 + l16) * 8]);
      const bf16x8 kc1 = ld8(&KBb[(size_t)((4 + quad) * 64 + ks * 16 + l16) * 8]);
#pragma unroll
      for (int r = 0; r < 4; r++) s[ks][r] = 0.f;
      s[ks] = __builtin_amdgcn_mfma_f32_16x16x32_bf16(kc0, aq0, s[ks], 0, 0, 0);
      s[ks] = __builtin_amdgcn_mfma_f32_16x16x32_bf16(kc1, aq1, s[ks], 0, 0, 0);
    }
    __builtin_amdgcn_s_setprio(0);

    if (kt == qt) {
#pragma unroll
      for (int ks = 0; ks < 4; ks++) {
#pragma unroll
        for (int r = 0; r < 4; r++) {
          const int kg = kt * 64 + ks * 16 + quad * 4 + r;
          if (kg > ql) s[ks][r] = -14427.0f;
        }
      }
    }

    // ---- online softmax (defer-max, THR=8 in exp2 domain) ----
    float tmax = s[0][0];
#pragma unroll
    for (int ks = 0; ks < 4; ks++)
#pragma unroll
      for (int r = 0; r < 4; r++) tmax = fmaxf(tmax, s[ks][r]);
    tmax = fmaxf(tmax, __shfl_xor(tmax, 16, 64));
    tmax = fmaxf(tmax, __shfl_xor(tmax, 32, 64));
    float mbase = m_run;
    if (__any(tmax - m_run > 8.0f)) {  // wave-uniform branch
      const float mnew = fmaxf(m_run, tmax);
      const float alpha = exp2f(m_run - mnew);
      m_run = mnew;
      mbase = mnew;
      l_run *= alpha;
#pragma unroll
      for (int d = 0; d < 4; d++)
#pragma unroll
        for (int r = 0; r < 4; r++) o_acc[d][r] *= alpha;
    }
    float rsum = 0.f;
    short4v pf[4];
#pragma unroll
    for (int ks = 0; ks < 4; ks++) {
#pragma unroll
      for (int r = 0; r < 4; r++) {
        const float pv = exp2f(s[ks][r] - mbase);
        rsum += pv;
        pf[ks][r] = bfbits(pv);
      }
    }
    rsum += __shfl_xor(rsum, 16, 64);
    rsum += __shfl_xor(rsum, 32, 64);
    l_run += rsum;

    // ---- PV ----
    __builtin_amdgcn_s_setprio(1);
#pragma unroll
    for (int d = 0; d < 4; d++) {
#pragma unroll
      for (int ks = 0; ks < 4; ks++) {
        const int gg = ks * 2 + (quad >> 1);
        const short4v av =
            *(const short4v*)&VBb[(size_t)(gg * 64 + d * 16 + l16) * 8 + (quad & 1) * 4];
        o_acc[d] = __builtin_amdgcn_mfma_f32_16x16x16bf16_1k(av, pf[ks], o_acc[d], 0, 0, 0);
      }
    }
    __builtin_amdgcn_s_setprio(0);

    __builtin_amdgcn_sched_barrier(0);
    __builtin_amdgcn_s_barrier();
  }

  const float inv_l = 1.f / fmaxf(l_run, 1e-30f);
  const size_t obase = (size_t)ql * (Nb * E) + (size_t)n * E + h * Dd;
#pragma unroll
  for (int d = 0; d < 4; d++)
#pragma unroll
    for (int r = 0; r < 4; r++)
      O[obase + d * 16 + quad * 4 + r] = __float2bfloat16(o_acc[d][r] * inv_l);
}

// ---------------------------------------------------------------------------
extern "C" void kernel_launch(void* const* d_in, const int* in_sizes, int n_in,
                              void* d_out, int out_size, void* d_ws, size_t ws_size,
                              hipStream_t stream) {
  const float* x    = (const float*)d_in[0];
  const float* ln1w = (const float*)d_in[1];
  const float* ln1b = (const float*)d_in[2];
  const float* wq   = (const float*)d_in[3];
  const float* bq   = (const float*)d_in[4];
  const float* wk   = (const float*)d_in[5];
  const float* bk   = (const float*)d_in[6];
  const float* wv   = (const float*)d_in[7];
  const float* bv   = (const float*)d_in[8];
  const float* wout = (const float*)d_in[9];
  const float* bout = (const float*)d_in[10];
  const float* ln2w = (const float*)d_in[11];
  const float* ln2b = (const float*)d_in[12];
  const float* fc1w = (const float*)d_in[13];
  const float* fc1b = (const float*)d_in[14];
  const float* fc2w = (const float*)d_in[15];
  const float* fc2b = (const float*)d_in[16];

  char* ws = (char*)d_ws;
  bf16* wqkvb = (bf16*)(ws);                        // 0-6 MB  [wq;wk;wv]
  bf16* woutb = (bf16*)(ws + ((size_t)6 << 20));    // 6-8 MB
  bf16* f1wb  = (bf16*)(ws + ((size_t)8 << 20));    // 8-16 MB
  bf16* f2wb  = (bf16*)(ws + ((size_t)16 << 20));   // 16-24 MB
  bf16* h1    = (bf16*)(ws + ((size_t)24 << 20));   // 24-32 MB (h2 reuses)
  bf16* qk1   = (bf16*)(ws + ((size_t)32 << 20));   // 32-40 MB Q [4096][1024]
  bf16* ktg   = (bf16*)(ws + ((size_t)40 << 20));   // 40-48 MB K packed
  bf16* vtg   = (bf16*)(ws + ((size_t)48 << 20));   // 48-56 MB V packed
  bf16* o     = (bf16*)(ws + ((size_t)56 << 20));   // 56-64 MB
  bf16* Pout  = (bf16*)(ws + ((size_t)32 << 20));   // 32-48: out-proj splitK (qk1/ktg dead)
  bf16* f1    = (bf16*)(ws + ((size_t)32 << 20));   // 32-64 (qk1,ktg,vtg,o dead)
  bf16* h2    = h1;
  // FC2 split-K4 partials (8 MB each), lifetimes checked:
  bf16* FP0   = (bf16*)(ws);                        // wqkvb/woutb dead after out-proj
  bf16* FP1   = (bf16*)(ws + ((size_t)8 << 20));    // f1wb dead after FC1
  bf16* FP2   = (bf16*)(ws + ((size_t)64 << 20));   // 64-72 free
  bf16* FP3   = (bf16*)(ws + ((size_t)72 << 20));   // 72-80 free
  float* outp = (float*)d_out;                      // holds f32 residual, then final

  cvt_all_kernel<<<12288, 256, 0, stream>>>(wq, wk, wv, wout, fc1w, fc2w,
                                            wqkvb, woutb, f1wb, f2wb);

  ln_kernel<<<MT, 256, 0, stream>>>(x, ln1w, ln1b, h1);

  // QKV: 128x256 TLP kernel, packed epilogue. q pre-scale folded with log2(e).
  gemm_tlp<1024, 1024, 3072, 4><<<dim3(12, 32), 512, 0, stream>>>(
      h1, wqkvb, bq, bk, bv, 0.125f * 1.44269504f, qk1, vtg, ktg, nullptr);

  attn_kernel<<<1024, 256, 0, stream>>>(qk1, ktg, vtg, o);

  // out-proj: split-K2 partials into Pout / Pout+MT*E
  gemm_tlp<512, 1024, 1024, 3><<<dim3(4, 32, 2), 512, 0, stream>>>(
      o, woutb, nullptr, nullptr, nullptr, 1.f,
      Pout, Pout + (size_t)MT * E, nullptr, nullptr);
  redln_kernel<<<MT, 256, 0, stream>>>(Pout, bout, x, ln2w, ln2b, outp, h2);

  // FC1: gelu epilogue
  gemm_tlp<1024, 1024, 4096, 2><<<dim3(16, 32), 512, 0, stream>>>(
      h2, f1wb, fc1b, nullptr, nullptr, 1.f, f1, nullptr, nullptr, nullptr);

  // FC2: split-K4 (512 blocks = 2/CU)
  gemm_tlp<1024, 4096, 1024, 3><<<dim3(4, 32, 4), 512, 0, stream>>>(
      f1, f2wb, nullptr, nullptr, nullptr, 1.f, FP0, FP1, FP2, FP3);
  reduce4_kernel<<<MT * E / 1024, 256, 0, stream>>>(FP0, FP1, FP2, FP3, fc2b, outp);
}